// Round 3
// baseline (1472.996 us; speedup 1.0000x reference)
//
#include <hip/hip_runtime.h>
#include <hip/hip_bf16.h>

using bf16 = __hip_bfloat16;
using bf16x2 = __hip_bfloat162;
typedef __attribute__((ext_vector_type(8))) short short8;
typedef __attribute__((ext_vector_type(4))) float f32x4;

__device__ __forceinline__ float b2f(bf16 v) { return __bfloat162float(v); }
__device__ __forceinline__ bf16 f2b(float v) { return __float2bfloat16(v); }

// async global->LDS, 16B per lane; dest must be wave-uniform base + lane*16
__device__ __forceinline__ void gload_lds16(const bf16* g, bf16* l)
{
    __builtin_amdgcn_global_load_lds(
        (const __attribute__((address_space(1))) void*)g,
        (__attribute__((address_space(3))) void*)l,
        16, 0, 0);
}

#define PH_BAR() do { __builtin_amdgcn_sched_barrier(0); __builtin_amdgcn_s_barrier(); __builtin_amdgcn_sched_barrier(0); } while (0)
#define WAIT_LGKM0() do { asm volatile("s_waitcnt lgkmcnt(0)" ::: "memory"); __builtin_amdgcn_sched_barrier(0); } while (0)
#define WAIT_VM0() do { asm volatile("s_waitcnt vmcnt(0)" ::: "memory"); __builtin_amdgcn_sched_barrier(0); } while (0)

// ---------------- NCHW f32 -> NHWC bf16 transpose (optionally halo-padded out) ----------------
__global__ __launch_bounds__(256) void nchw_to_nhwc(const float* __restrict__ in,
                                                    bf16* __restrict__ out,
                                                    int C, int H, int W, int pad)
{
    __shared__ bf16 tile[64][68];
    const int S = H * W;
    const int HP = H + 2 * pad, WP = W + 2 * pad;
    const int b = blockIdx.x, s0 = blockIdx.y * 64, c0 = blockIdx.z * 64;
    const int t = threadIdx.x;
    const int a = t & 63, q = t >> 6;
#pragma unroll
    for (int i = 0; i < 16; ++i) {
        int cl = q + i * 4;
        int s = s0 + a;
        tile[cl][a] = (s < S) ? f2b(in[((size_t)b * C + c0 + cl) * S + s]) : f2b(0.f);
    }
    __syncthreads();
#pragma unroll
    for (int i = 0; i < 16; ++i) {
        int sl = q + i * 4;
        int s = s0 + sl;
        if (s < S) {
            int y = s / W, x = s - (s / W) * W;
            out[(((size_t)b * HP + y + pad) * WP + x + pad) * C + c0 + a] = tile[a][sl];
        }
    }
}

// ---------------- zero the 1-px halo of a padded NHWC buffer ----------------
__global__ __launch_bounds__(256) void halo_zero(bf16* __restrict__ buf, int W, int C)
{
    const int b = blockIdx.x, y = blockIdx.y;
    const int P = W + 2;
    const bf16 z = f2b(0.f);
    bf16* row = buf + ((size_t)b * P + y) * P * C;
    if (y == 0 || y == P - 1) {
        for (int i = threadIdx.x; i < P * C; i += 256) row[i] = z;
    } else {
        for (int i = threadIdx.x; i < 2 * C; i += 256) {
            const int x = (i < C) ? 0 : P - 1;
            const int c = (i < C) ? i : i - C;
            row[(size_t)x * C + c] = z;
        }
    }
}

// ---------------- pack NHWC bf16 halves -> NCHW f32 concat output ----------------
__global__ __launch_bounds__(256) void pack_out(const bf16* __restrict__ x1o,
                                                const bf16* __restrict__ x2o,
                                                float* __restrict__ out)
{
    __shared__ bf16 tile[64][68];
    const int b = blockIdx.x, s0 = blockIdx.y * 64, ch0 = blockIdx.z * 64;
    const bf16* src = (ch0 < 512) ? x1o : x2o;
    const int c0 = ch0 & 511;
    const int t = threadIdx.x;
    const int a = t & 63, q = t >> 6;
#pragma unroll
    for (int i = 0; i < 16; ++i) {
        int sl = q + i * 4;
        tile[sl][a] = src[((size_t)b * 1600 + s0 + sl) * 512 + c0 + a];
    }
    __syncthreads();
#pragma unroll
    for (int i = 0; i < 16; ++i) {
        int cl = q + i * 4;
        out[((size_t)b * 1024 + ch0 + cl) * 1600 + s0 + a] = b2f(tile[a][cl]);
    }
}

// ------- weight reorder+convert: w[o][c][ky][kx] f32 -> wr[o][(ky*3+kx)*C + c] bf16 -------
__global__ __launch_bounds__(256) void reorder_w(const float* __restrict__ w,
                                                 bf16* __restrict__ wr,
                                                 int C, int total)
{
    int i = blockIdx.x * 256 + threadIdx.x;
    if (i >= total) return;
    int nineC = 9 * C;
    int o = i / nineC;
    int r = i - o * nineC;
    int tap = r / C;
    int c = r - tap * C;
    wr[i] = f2b(w[((size_t)o * C + c) * 9 + tap]);
}

// ---------------- plain f32 -> bf16 convert ----------------
__global__ __launch_bounds__(256) void f32_to_bf16(const float* __restrict__ in,
                                                   bf16* __restrict__ out, int n)
{
    int i = blockIdx.x * 256 + threadIdx.x;
    if (i < n) out[i] = f2b(in[i]);
}

// ---------------- patch mean pool: x2 NHWC -> kp[b*100][512] bf16 ----------------
__global__ __launch_bounds__(256) void pool_kp(const bf16* __restrict__ x2n,
                                               bf16* __restrict__ kp)
{
    const int p = blockIdx.x;            // b*100 + l
    const int b = p / 100, l = p - (p / 100) * 100;
    const int ph = l / 10, pw = l - (l / 10) * 10;
    const int t = threadIdx.x;           // 256 threads, 2 channels each
    const bf16x2* base = (const bf16x2*)(x2n + (((size_t)(b * 40 + ph * 4) * 40) + pw * 4) * 512) + t;
    float sx = 0.f, sy = 0.f;
#pragma unroll
    for (int py = 0; py < 4; ++py)
#pragma unroll
        for (int px = 0; px < 4; ++px) {
            float2 v = __bfloat1622float2(base[(py * 40 + px) * 256]);
            sx += v.x; sy += v.y;
        }
    ((bf16x2*)(kp + (size_t)p * 512))[t] = __float22bfloat162_rn(make_float2(sx * 0.0625f, sy * 0.0625f));
}

// ---------------- channel-attention MLP at 20x20 source resolution ----------------
__global__ __launch_bounds__(256) void ca_mlp(const bf16* __restrict__ x1n,
                                              const float* __restrict__ w1, const float* __restrict__ b1,
                                              const float* __restrict__ w2, const float* __restrict__ b2,
                                              bf16* __restrict__ xca)
{
    __shared__ float a1v[256];
    __shared__ float part[4][64];
    __shared__ float hid[64];
    const int blk = blockIdx.x;
    const int b = blk / 400;
    const int rem = blk - b * 400;
    const int y = rem / 20, x = rem - (rem / 20) * 20;
    const int t = threadIdx.x;
    const bf16* src = x1n + ((size_t)(b * 22 + y + 1) * 22 + x + 1) * 512 + 256;
    a1v[t] = b2f(src[t]);
    __syncthreads();
    {
        const int h = t & 63, seg = t >> 6;
        float acc = 0.f;
        const float* wp = w1 + (size_t)h * 256 + seg * 64;
        const float* ap = a1v + seg * 64;
#pragma unroll 8
        for (int c = 0; c < 64; ++c) acc += wp[c] * ap[c];
        part[seg][h] = acc;
    }
    __syncthreads();
    if (t < 64)
        hid[t] = fmaxf(part[0][t] + part[1][t] + part[2][t] + part[3][t] + b1[t], 0.f);
    __syncthreads();
    float acc2 = b2[t];
    const float* w2p = w2 + (size_t)t * 64;
#pragma unroll 8
    for (int h = 0; h < 64; ++h) acc2 += w2p[h] * hid[h];
    const float g = 1.f / (1.f + __expf(-acc2));
    const bf16 o = f2b(a1v[t] * g);
    const size_t obase = ((size_t)(b * 42 + 2 * y + 1) * 42 + 2 * x + 1) * 256 + t;
    xca[obase] = o;
    xca[obase + 256] = o;
    xca[obase + 42 * 256] = o;
    xca[obase + 42 * 256 + 256] = o;
}

// ---------------- attention: one block per (batch,head) ----------------
__global__ __launch_bounds__(256, 1)
void attn_kernel(const float* __restrict__ q, const float* __restrict__ k,
                 const bf16* __restrict__ x2n, bf16* __restrict__ attn)
{
    __shared__ float sc[100][100];
    __shared__ bf16 wT[100][104];   // wT[l][ql]
    const int t = threadIdx.x;
    const int n = blockIdx.x;
    const int b = n >> 3, hd = n & 7;
    const float* qn = q + (size_t)n * 3200;
    const float* kn = k + (size_t)n * 3200;
    for (int e = t; e < 10000; e += 256) {
        const int i = e / 100;
        const int j = e - i * 100;
        const float4* qa = (const float4*)(qn + i * 32);
        const float4* ka = (const float4*)(kn + j * 32);
        float d = 0.f;
#pragma unroll
        for (int u = 0; u < 8; ++u) {
            float4 xv = qa[u], yv = ka[u];
            d += xv.x * yv.x + xv.y * yv.y + xv.z * yv.z + xv.w * yv.w;
        }
        sc[i][j] = d * 0.17677669529663687f;   // 1/sqrt(32)
    }
    __syncthreads();
    if (t < 100) {
        float mx = -1e30f;
        for (int j = 0; j < 100; ++j) mx = fmaxf(mx, sc[t][j]);
        float s = 0.f;
        for (int j = 0; j < 100; ++j) s += __expf(sc[t][j] - mx);
        const float inv = 1.f / s;
        for (int j = 0; j < 100; ++j) wT[j][t] = f2b(__expf(sc[t][j] - mx) * inv);
    }
    __syncthreads();
    const int ch0 = (t & 15) * 4;
    const int pix = t >> 4;
    const int py = pix >> 2, px = pix & 3;
    const bf16* vbase = x2n + (((size_t)(b * 40 + py) * 40) + px) * 512 + hd * 64 + ch0;
    for (int ql0 = 0; ql0 < 100; ql0 += 20) {
        float2 a0[20], a1[20];
#pragma unroll
        for (int i = 0; i < 20; ++i) { a0[i] = make_float2(0.f, 0.f); a1[i] = make_float2(0.f, 0.f); }
        for (int l = 0; l < 100; ++l) {
            const int ph = l / 10, pw = l - (l / 10) * 10;
            const bf16* vp = vbase + ((size_t)(ph * 160 + pw * 4)) * 512;
            const float2 v01 = __bfloat1622float2(*(const bf16x2*)vp);
            const float2 v23 = __bfloat1622float2(*(const bf16x2*)(vp + 2));
            const bf16x2* wp = (const bf16x2*)&wT[l][ql0];
#pragma unroll
            for (int ii = 0; ii < 10; ++ii) {
                const float2 w2 = __bfloat1622float2(wp[ii]);
                a0[ii * 2 + 0].x += w2.x * v01.x; a0[ii * 2 + 0].y += w2.x * v01.y;
                a1[ii * 2 + 0].x += w2.x * v23.x; a1[ii * 2 + 0].y += w2.x * v23.y;
                a0[ii * 2 + 1].x += w2.y * v01.x; a0[ii * 2 + 1].y += w2.y * v01.y;
                a1[ii * 2 + 1].x += w2.y * v23.x; a1[ii * 2 + 1].y += w2.y * v23.y;
            }
        }
#pragma unroll
        for (int i = 0; i < 20; ++i) {
            const int ql = ql0 + i;
            const int ph = ql / 10, pw = ql - (ql / 10) * 10;
            bf16* op = attn + (((size_t)(b * 42 + ph * 4 + py + 1) * 42) + pw * 4 + px + 1) * 512 + hd * 64 + ch0;
            *(bf16x2*)op = __float22bfloat162_rn(a0[i]);
            *(bf16x2*)(op + 2) = __float22bfloat162_rn(a1[i]);
        }
    }
}

enum ConvMode { M_QCONV = 0, M_SA1 = 1, M_SA2 = 2, M_C3 = 3, M_CONV2 = 4, M_KPROJ = 5 };

// ---------------- small-M implicit-GEMM MFMA conv (128x128 tile) for QCONV/KPROJ ----------------
template <int MODE>
__global__ __launch_bounds__(256, 2)
void conv_mfma(const bf16* __restrict__ in, const bf16* __restrict__ wr,
               const float* __restrict__ scale, const float* __restrict__ bias,
               float* __restrict__ outf)
{
    constexpr int CIN  = 512;
    constexpr int TAPS = (MODE == M_KPROJ) ? 1 : 9;
    constexpr int STR  = 2;
    constexpr int HP   = 22;
    constexpr int WOUT = 10;
    constexpr int K    = TAPS * CIN;
    constexpr int KD   = (TAPS == 9) ? 3 : 1;

    __shared__ bf16 Al[128][64];
    __shared__ bf16 Bl[128][64];

    const int t = threadIdx.x;
    const int p0 = blockIdx.x * 128;
    const int n0 = blockIdx.y * 128;

    int s_row[4], s_dst8[4], s_src8[4], s_b[4], s_oy[4], s_ox[4];
    const bf16* bB[4];
#pragma unroll
    for (int i = 0; i < 4; ++i) {
        const int task = t + i * 256;
        const int row = task >> 3, chk = task & 7;
        s_row[i] = row;
        s_dst8[i] = chk * 8;
        s_src8[i] = (chk ^ (row & 7)) * 8;
        const int p = p0 + row;
        const int bb = p / 100;
        const int s = p - bb * 100;
        s_b[i] = bb;
        s_oy[i] = s / WOUT;
        s_ox[i] = s - s_oy[i] * WOUT;
        bB[i] = wr + (size_t)(n0 + row) * K + s_src8[i];
    }

    const bf16* aP1[4];
    if (MODE == M_KPROJ) {
#pragma unroll
        for (int i = 0; i < 4; ++i)
            aP1[i] = in + (size_t)(p0 + s_row[i]) * 512 + s_src8[i];
    }

    const int lane = t & 63;
    const int wv = t >> 6;
    const int m_off = (wv >> 1) * 64;
    const int n_off = (wv & 1) * 64;
    const int fr = lane & 15;
    const int qd = lane >> 4;
    const int xa = (fr & 7) << 4;

    f32x4 acc[4][4];
#pragma unroll
    for (int mi = 0; mi < 4; ++mi)
#pragma unroll
        for (int ni = 0; ni < 4; ++ni)
            acc[mi][ni] = (f32x4){0.f, 0.f, 0.f, 0.f};

    for (int ky = 0; ky < KD; ++ky)
    for (int kx = 0; kx < KD; ++kx) {
        const bf16* aT[4];
        if (TAPS == 9) {
#pragma unroll
            for (int i = 0; i < 4; ++i)
                aT[i] = in + ((size_t)((s_b[i] * HP + s_oy[i] * STR + ky) * HP) + s_ox[i] * STR + kx) * CIN + s_src8[i];
        }
        const int kk0 = (ky * KD + kx) * CIN;
        for (int c0 = 0; c0 < CIN; c0 += 64) {
#pragma unroll
            for (int i = 0; i < 4; ++i) {
                const bf16* sa = (MODE == M_KPROJ) ? (aP1[i] + c0) : (aT[i] + c0);
                gload_lds16(sa, &Al[s_row[i]][s_dst8[i]]);
            }
#pragma unroll
            for (int i = 0; i < 4; ++i)
                gload_lds16(bB[i] + (kk0 + c0), &Bl[s_row[i]][s_dst8[i]]);
            __syncthreads();
#pragma unroll
            for (int ks = 0; ks < 2; ++ks) {
                short8 af[4], bfr[4];
                const int coff = (ks * 64 + qd * 16) ^ xa;
#pragma unroll
                for (int mi = 0; mi < 4; ++mi)
                    af[mi] = *(const short8*)((const char*)&Al[m_off + mi * 16 + fr][0] + coff);
#pragma unroll
                for (int ni = 0; ni < 4; ++ni)
                    bfr[ni] = *(const short8*)((const char*)&Bl[n_off + ni * 16 + fr][0] + coff);
#pragma unroll
                for (int mi = 0; mi < 4; ++mi)
#pragma unroll
                    for (int ni = 0; ni < 4; ++ni)
                        acc[mi][ni] = __builtin_amdgcn_mfma_f32_16x16x32_bf16(af[mi], bfr[ni], acc[mi][ni], 0, 0, 0);
            }
            __syncthreads();
        }
    }

#pragma unroll
    for (int ni = 0; ni < 4; ++ni) {
        const int nn = n0 + n_off + ni * 16 + fr;
        float scv = 1.f, bsv = 0.f;
        if (MODE != M_KPROJ) { scv = scale[nn]; bsv = bias[nn]; }
#pragma unroll
        for (int mi = 0; mi < 4; ++mi) {
            const int mb = p0 + m_off + mi * 16 + qd * 4;
#pragma unroll
            for (int r = 0; r < 4; ++r) {
                const int p = mb + r;
                const float v = acc[mi][ni][r];
                const int bb = p / 100, l = p - (p / 100) * 100;
                if (MODE == M_KPROJ) {
                    outf[(((size_t)(bb * 8 + (nn >> 5))) * 100 + l) * 32 + (nn & 31)] = v;
                } else {
                    const float y = v * scv + bsv;
                    const float a = y / (1.f + __expf(-y));
                    outf[(((size_t)(bb * 8 + (nn >> 5))) * 100 + l) * 32 + (nn & 31)] = a;
                }
            }
        }
    }
}

// ---------------- big-M conv: 256x256 tile, 512 threads, 4-phase pipelined schedule ----------------
template <int MODE>
__global__ __launch_bounds__(512, 2)
void conv_mfma256(const bf16* __restrict__ in, const bf16* __restrict__ in2,
                  const bf16* __restrict__ wr,
                  const float* __restrict__ scale, const float* __restrict__ bias,
                  const bf16* __restrict__ resid,
                  bf16* __restrict__ outb)
{
    constexpr int CIN  = (MODE == M_C3) ? 512 : (MODE == M_CONV2 ? 768 : 256);
    constexpr int TAPS = (MODE == M_CONV2) ? 1 : 9;
    constexpr int K    = TAPS * CIN;
    constexpr int NT   = K / 64;
    constexpr int CPT  = CIN / 64;          // 4 or 8 for TAPS==9
    constexpr int L2C  = (CPT == 8) ? 3 : 2;
    constexpr int HP   = 42;

    __shared__ bf16 Al[2][256][64];
    __shared__ bf16 Bl[2][256][64];

    const int t = threadIdx.x;
    const int p0 = blockIdx.x * 256;
    const int n0 = blockIdx.y * 256;

    const int row64 = t >> 3;
    const int chk = t & 7;
    const int src8 = (chk ^ (row64 & 7)) * 8;   // pre-swizzled global chunk
    const int dst8 = chk * 8;                   // linear LDS chunk

    // per-thread A-row decodes for the 4 A staging issues
    const bf16* aBase[4];
    const bf16* aBase2[4];
#pragma unroll
    for (int si = 0; si < 4; ++si) {
        const int p = p0 + si * 64 + row64;
        const int b = p / 1600;
        const int s = p - b * 1600;
        const int oy = s / 40, ox = s - (s / 40) * 40;
        if (MODE == M_CONV2) {
            aBase[si]  = in  + ((size_t)(b * 22 + (oy >> 1) + 1) * 22 + (ox >> 1) + 1) * 512 + src8;
            aBase2[si] = in2 + ((size_t)(b * 1600 + oy * 40 + ox)) * 256 + src8;
        } else {
            aBase[si]  = in  + ((size_t)(b * HP + oy) * HP + ox) * CIN + src8;
            aBase2[si] = nullptr;
        }
    }
    const bf16* bBase[4];
#pragma unroll
    for (int si = 0; si < 4; ++si)
        bBase[si] = wr + (size_t)(n0 + si * 64 + row64) * K + src8;

    const int lane = t & 63;
    const int wv = t >> 6;
    const int m_off = (wv >> 2) * 128;      // 2 wave-rows
    const int n_off = (wv & 3) * 64;        // 4 wave-cols
    const int fr = lane & 15;
    const int qd = lane >> 4;
    const int xa = (fr & 7) << 4;

    f32x4 acc[8][4];
#pragma unroll
    for (int mi = 0; mi < 8; ++mi)
#pragma unroll
        for (int ni = 0; ni < 4; ++ni)
            acc[mi][ni] = (f32x4){0.f, 0.f, 0.f, 0.f};

#define LDA8(buf, rrow, kkk) \
    (*(const short8*)((const char*)&Al[buf][rrow][0] + ((((kkk) * 64) + qd * 16) ^ xa)))
#define LDB8(buf, rrow, kkk) \
    (*(const short8*)((const char*)&Bl[buf][rrow][0] + ((((kkk) * 64) + qd * 16) ^ xa)))

    // ---- prologue: stage K-tile 0 into buffer 0 ----
#pragma unroll
    for (int si = 0; si < 4; ++si)
        gload_lds16(aBase[si], &Al[0][si * 64 + row64][dst8]);
#pragma unroll
    for (int si = 0; si < 4; ++si)
        gload_lds16(bBase[si], &Bl[0][si * 64 + row64][dst8]);
    asm volatile("s_waitcnt vmcnt(0)" ::: "memory");
    __syncthreads();

#pragma clang loop unroll(disable)
    for (int kt = 0; kt < NT; ++kt) {
        const int cur = kt & 1;
        const int nxt = cur ^ 1;
        const int ktn = kt + 1;
        const bool pf = (ktn < NT);
        int offAn = 0, c0n = 0;
        if (pf) {
            if (MODE == M_CONV2) {
                c0n = ktn * 64;
            } else {
                const int tap = ktn >> L2C;
                const int ci = ktn & (CPT - 1);
                const int ky = tap / 3, kx = tap - ky * 3;
                offAn = (ky * HP + kx) * CIN + ci * 64;
            }
        }
        const int offBn = ktn * 64;

        auto stage = [&](int si) {
            if (si < 4) {
                const bf16* sa;
                if (MODE == M_CONV2) sa = (c0n < 512) ? (aBase[si] + c0n) : (aBase2[si] + (c0n - 512));
                else sa = aBase[si] + offAn;
                gload_lds16(sa, &Al[nxt][si * 64 + row64][dst8]);
            } else {
                gload_lds16(bBase[si - 4] + offBn, &Bl[nxt][(si - 4) * 64 + row64][dst8]);
            }
        };

        short8 af[4][2], bf0[2][2], bf1[2][2];

        // ===== phase 0: A(h=0) + B(j=0) reads; stage 0-2; MFMA quad (0,0) =====
#pragma unroll
        for (int m4 = 0; m4 < 4; ++m4) {
            af[m4][0] = LDA8(cur, m_off + m4 * 16 + fr, 0);
            af[m4][1] = LDA8(cur, m_off + m4 * 16 + fr, 1);
        }
#pragma unroll
        for (int n2 = 0; n2 < 2; ++n2) {
            bf0[n2][0] = LDB8(cur, n_off + n2 * 16 + fr, 0);
            bf0[n2][1] = LDB8(cur, n_off + n2 * 16 + fr, 1);
        }
        if (pf) { stage(0); stage(1); stage(2); }
        PH_BAR();
        WAIT_LGKM0();
        __builtin_amdgcn_s_setprio(1);
#pragma unroll
        for (int m4 = 0; m4 < 4; ++m4)
#pragma unroll
            for (int n2 = 0; n2 < 2; ++n2) {
                acc[m4][n2] = __builtin_amdgcn_mfma_f32_16x16x32_bf16(af[m4][0], bf0[n2][0], acc[m4][n2], 0, 0, 0);
                acc[m4][n2] = __builtin_amdgcn_mfma_f32_16x16x32_bf16(af[m4][1], bf0[n2][1], acc[m4][n2], 0, 0, 0);
            }
        __builtin_amdgcn_s_setprio(0);
        PH_BAR();

        // ===== phase 1: B(j=1) reads; stage 3-5; MFMA quad (0,1) =====
#pragma unroll
        for (int n2 = 0; n2 < 2; ++n2) {
            bf1[n2][0] = LDB8(cur, n_off + (2 + n2) * 16 + fr, 0);
            bf1[n2][1] = LDB8(cur, n_off + (2 + n2) * 16 + fr, 1);
        }
        if (pf) { stage(3); stage(4); stage(5); }
        PH_BAR();
        WAIT_LGKM0();
        __builtin_amdgcn_s_setprio(1);
#pragma unroll
        for (int m4 = 0; m4 < 4; ++m4)
#pragma unroll
            for (int n2 = 0; n2 < 2; ++n2) {
                acc[m4][2 + n2] = __builtin_amdgcn_mfma_f32_16x16x32_bf16(af[m4][0], bf1[n2][0], acc[m4][2 + n2], 0, 0, 0);
                acc[m4][2 + n2] = __builtin_amdgcn_mfma_f32_16x16x32_bf16(af[m4][1], bf1[n2][1], acc[m4][2 + n2], 0, 0, 0);
            }
        __builtin_amdgcn_s_setprio(0);
        PH_BAR();

        // ===== phase 2: A(h=1) reads; stage 6-7; MFMA quad (1,0) =====
#pragma unroll
        for (int m4 = 0; m4 < 4; ++m4) {
            af[m4][0] = LDA8(cur, m_off + (4 + m4) * 16 + fr, 0);
            af[m4][1] = LDA8(cur, m_off + (4 + m4) * 16 + fr, 1);
        }
        if (pf) { stage(6); stage(7); }
        PH_BAR();
        WAIT_LGKM0();
        __builtin_amdgcn_s_setprio(1);
#pragma unroll
        for (int m4 = 0; m4 < 4; ++m4)
#pragma unroll
            for (int n2 = 0; n2 < 2; ++n2) {
                acc[4 + m4][n2] = __builtin_amdgcn_mfma_f32_16x16x32_bf16(af[m4][0], bf0[n2][0], acc[4 + m4][n2], 0, 0, 0);
                acc[4 + m4][n2] = __builtin_amdgcn_mfma_f32_16x16x32_bf16(af[m4][1], bf0[n2][1], acc[4 + m4][n2], 0, 0, 0);
            }
        __builtin_amdgcn_s_setprio(0);
        PH_BAR();

        // ===== phase 3: MFMA quad (1,1); drain vmcnt; K-tile boundary barrier =====
        __builtin_amdgcn_s_setprio(1);
#pragma unroll
        for (int m4 = 0; m4 < 4; ++m4)
#pragma unroll
            for (int n2 = 0; n2 < 2; ++n2) {
                acc[4 + m4][2 + n2] = __builtin_amdgcn_mfma_f32_16x16x32_bf16(af[m4][0], bf1[n2][0], acc[4 + m4][2 + n2], 0, 0, 0);
                acc[4 + m4][2 + n2] = __builtin_amdgcn_mfma_f32_16x16x32_bf16(af[m4][1], bf1[n2][1], acc[4 + m4][2 + n2], 0, 0, 0);
            }
        __builtin_amdgcn_s_setprio(0);
        WAIT_VM0();
        PH_BAR();
    }
#undef LDA8
#undef LDB8

    // ---- epilogue ----
#pragma unroll
    for (int ni = 0; ni < 4; ++ni) {
        const int nn = n0 + n_off + ni * 16 + fr;
        const float scv = scale[nn];
        const float bsv = bias[nn];
#pragma unroll
        for (int mi = 0; mi < 8; ++mi) {
            const int mb = p0 + m_off + mi * 16 + qd * 4;
#pragma unroll
            for (int r = 0; r < 4; ++r) {
                const int p = mb + r;
                const float y = acc[mi][ni][r] * scv + bsv;
                const float a = y / (1.f + __expf(-y));
                if (MODE == M_SA1) {
                    const int bb = p / 1600; const int s = p - bb * 1600;
                    const int oy = s / 40, ox = s - (s / 40) * 40;
                    outb[(((size_t)(bb * 42 + oy + 1)) * 42 + ox + 1) * 256 + nn] = f2b(a);
                } else if (MODE == M_SA2) {
                    const int bb = p / 1600; const int s = p - bb * 1600;
                    const int oy = s / 40, ox = s - (s / 40) * 40;
                    const size_t roff = (((size_t)(bb * 42 + oy + 1)) * 42 + ox + 1) * 256 + nn;
                    outb[(size_t)p * 256 + nn] = f2b(a + b2f(resid[roff]));
                } else if (MODE == M_C3) {
                    const int bb = p / 1600; const int s = p - bb * 1600;
                    const int oy = s / 40, ox = s - (s / 40) * 40;
                    const size_t roff = (((size_t)(bb * 42 + oy + 1)) * 42 + ox + 1) * 512 + nn;
                    outb[(size_t)p * 512 + nn] = f2b(a + b2f(resid[roff]));
                } else { // M_CONV2
                    outb[(size_t)p * 512 + nn] = f2b(a);
                }
            }
        }
    }
}

extern "C" void kernel_launch(void* const* d_in, const int* in_sizes, int n_in,
                              void* d_out, int out_size, void* d_ws, size_t ws_size,
                              hipStream_t stream)
{
    const float* x1      = (const float*)d_in[0];
    const float* x2      = (const float*)d_in[1];
    const float* q_w     = (const float*)d_in[2];
    const float* q_s     = (const float*)d_in[3];
    const float* q_b     = (const float*)d_in[4];
    const float* key_w   = (const float*)d_in[5];
    const float* ca_w1   = (const float*)d_in[6];
    const float* ca_b1   = (const float*)d_in[7];
    const float* ca_w2   = (const float*)d_in[8];
    const float* ca_b2   = (const float*)d_in[9];
    const float* sa1_w   = (const float*)d_in[10];
    const float* sa1_s   = (const float*)d_in[11];
    const float* sa1_b   = (const float*)d_in[12];
    const float* sa2_w   = (const float*)d_in[13];
    const float* sa2_s   = (const float*)d_in[14];
    const float* sa2_b   = (const float*)d_in[15];
    const float* conv2_w = (const float*)d_in[16];
    const float* conv2_s = (const float*)d_in[17];
    const float* conv2_b = (const float*)d_in[18];
    const float* c3_w    = (const float*)d_in[19];
    const float* c3_s    = (const float*)d_in[20];
    const float* c3_b    = (const float*)d_in[21];

    char* ws = (char*)d_ws;
    // workspace layout (bytes) — padded NHWC buffers, aggressive aliasing
    const size_t o_x1n  = 0;                 // 32*22*22*512 bf16 : 15,859,712 (halo)
    const size_t o_x2n  = 15859712;          // 32*1600*512 bf16  : 52,428,800 (x2o alias after attn)
    const size_t o_attn = 68288512;          // 32*42*42*512 bf16 : 57,802,752 (halo; x1o alias after C3)
    const size_t o_xca  = 126091264;         // 32*42*42*256 bf16 : 28,901,376 (halo; wc3 alias after SA2)
    const size_t o_tbuf = 154992640;         // 32*42*42*256 bf16 : 28,901,376 (halo; k/q/wkey alias before SA1)
    const size_t o_a2   = 183894016;         // 32*1600*256 bf16  : 26,214,400 (kp/wq alias before SA2)
    const size_t o_ws1  = 210108416;         // 256*2304 bf16 : 1,179,648
    const size_t o_ws2  = 211288064;         // 256*2304 bf16 : 1,179,648
    const size_t o_wc2  = 212467712;         // 512*768  bf16 :   786,432
    // aliases
    const size_t o_k    = o_tbuf;            // 3,276,800 f32
    const size_t o_q    = o_tbuf + 3276800;  // 3,276,800 f32
    const size_t o_wkey = o_tbuf + 6553600;  //   262,144 bf16
    const size_t o_kp   = o_a2;              // 3,276,800 bf16
    const size_t o_wq   = o_a2 + 3276800;    // 2,359,296 bf16
    const size_t o_wc3  = o_xca;             // 4,718,592 bf16

    bf16*  x1n    = (bf16*)(ws + o_x1n);
    bf16*  x2n    = (bf16*)(ws + o_x2n);
    float* k_attn = (float*)(ws + o_k);
    float* q_attn = (float*)(ws + o_q);
    bf16*  attn   = (bf16*)(ws + o_attn);
    bf16*  xca    = (bf16*)(ws + o_xca);
    bf16*  tbuf   = (bf16*)(ws + o_tbuf);
    bf16*  a2     = (bf16*)(ws + o_a2);
    bf16*  wq     = (bf16*)(ws + o_wq);
    bf16*  wc3    = (bf16*)(ws + o_wc3);
    bf16*  wsa1   = (bf16*)(ws + o_ws1);
    bf16*  wsa2   = (bf16*)(ws + o_ws2);
    bf16*  kp     = (bf16*)(ws + o_kp);
    bf16*  wkey   = (bf16*)(ws + o_wkey);
    bf16*  wc2    = (bf16*)(ws + o_wc2);
    bf16*  x2o    = (bf16*)(ws + o_x2n);     // alias: x2n dead after attn_kernel
    bf16*  x1o    = (bf16*)(ws + o_attn);    // alias: attn dead after C3

    const dim3 blk(256);
    const dim3 blk512(512);

    halo_zero<<<dim3(32, 22), blk, 0, stream>>>(x1n, 20, 512);
    halo_zero<<<dim3(32, 42), blk, 0, stream>>>(xca, 40, 256);
    halo_zero<<<dim3(32, 42), blk, 0, stream>>>(attn, 40, 512);

    nchw_to_nhwc<<<dim3(32, 7, 8), blk, 0, stream>>>(x1, x1n, 512, 20, 20, 1);
    nchw_to_nhwc<<<dim3(32, 25, 8), blk, 0, stream>>>(x2, x2n, 512, 40, 40, 0);
    reorder_w<<<4608, blk, 0, stream>>>(q_w,  wq,   512, 256 * 512 * 9);
    reorder_w<<<2304, blk, 0, stream>>>(sa1_w, wsa1, 256, 256 * 256 * 9);
    reorder_w<<<2304, blk, 0, stream>>>(sa2_w, wsa2, 256, 256 * 256 * 9);
    f32_to_bf16<<<512, blk, 0, stream>>>(key_w, wkey, 256 * 512);
    f32_to_bf16<<<1536, blk, 0, stream>>>(conv2_w, wc2, 512 * 768);
    pool_kp<<<3200, blk, 0, stream>>>(x2n, kp);

    conv_mfma<M_KPROJ><<<dim3(25, 2), blk, 0, stream>>>(kp, wkey, nullptr, nullptr, k_attn);
    conv_mfma<M_QCONV><<<dim3(25, 2), blk, 0, stream>>>(x1n, wq, q_s, q_b, q_attn);

    attn_kernel<<<256, blk, 0, stream>>>(q_attn, k_attn, x2n, attn);

    // k/q/wkey dead now; zero tbuf halo before SA1/SA2 use it
    halo_zero<<<dim3(32, 42), blk, 0, stream>>>(tbuf, 40, 256);

    ca_mlp<<<12800, blk, 0, stream>>>(x1n, ca_w1, ca_b1, ca_w2, ca_b2, xca);

    conv_mfma256<M_SA1><<<dim3(200, 1), blk512, 0, stream>>>(xca, nullptr, wsa1,
        sa1_s, sa1_b, nullptr, tbuf);
    conv_mfma256<M_SA2><<<dim3(200, 1), blk512, 0, stream>>>(tbuf, nullptr, wsa2,
        sa2_s, sa2_b, xca, a2);

    // xca dead; build wc3 in its slot just before C3
    reorder_w<<<9216, blk, 0, stream>>>(c3_w, wc3, 512, 512 * 512 * 9);
    conv_mfma256<M_C3><<<dim3(200, 2), blk512, 0, stream>>>(attn, nullptr, wc3,
        c3_s, c3_b, attn, x2o);
    conv_mfma256<M_CONV2><<<dim3(200, 2), blk512, 0, stream>>>(x1n, a2, wc2,
        conv2_s, conv2_b, nullptr, x1o);

    pack_out<<<dim3(32, 25, 16), blk, 0, stream>>>(x1o, x2o, (float*)d_out);

    (void)in_sizes; (void)n_in; (void)out_size; (void)ws_size;
}

// Round 4
// 1427.152 us; speedup vs baseline: 1.0321x; 1.0321x over previous
//
#include <hip/hip_runtime.h>
#include <hip/hip_bf16.h>

using bf16 = __hip_bfloat16;
using bf16x2 = __hip_bfloat162;
typedef __attribute__((ext_vector_type(8))) short short8;
typedef __attribute__((ext_vector_type(4))) float f32x4;

__device__ __forceinline__ float b2f(bf16 v) { return __bfloat162float(v); }
__device__ __forceinline__ bf16 f2b(float v) { return __float2bfloat16(v); }

// async global->LDS, 16B per lane; dest must be wave-uniform base + lane*16
__device__ __forceinline__ void gload_lds16(const bf16* g, bf16* l)
{
    __builtin_amdgcn_global_load_lds(
        (const __attribute__((address_space(1))) void*)g,
        (__attribute__((address_space(3))) void*)l,
        16, 0, 0);
}

#define PH_BAR() do { __builtin_amdgcn_sched_barrier(0); __builtin_amdgcn_s_barrier(); __builtin_amdgcn_sched_barrier(0); } while (0)
#define WAIT_LGKM0() do { asm volatile("s_waitcnt lgkmcnt(0)" ::: "memory"); __builtin_amdgcn_sched_barrier(0); } while (0)
#define WAIT_VM0() do { asm volatile("s_waitcnt vmcnt(0)" ::: "memory"); __builtin_amdgcn_sched_barrier(0); } while (0)
#define WAIT_VM2() do { asm volatile("s_waitcnt vmcnt(2)" ::: "memory"); __builtin_amdgcn_sched_barrier(0); } while (0)
#define WAIT_VM4() do { asm volatile("s_waitcnt vmcnt(4)" ::: "memory"); __builtin_amdgcn_sched_barrier(0); } while (0)

// ---------------- NCHW f32 -> NHWC bf16 transpose (optionally halo-padded out) ----------------
__global__ __launch_bounds__(256) void nchw_to_nhwc(const float* __restrict__ in,
                                                    bf16* __restrict__ out,
                                                    int C, int H, int W, int pad)
{
    __shared__ bf16 tile[64][68];
    const int S = H * W;
    const int HP = H + 2 * pad, WP = W + 2 * pad;
    const int b = blockIdx.x, s0 = blockIdx.y * 64, c0 = blockIdx.z * 64;
    const int t = threadIdx.x;
    const int a = t & 63, q = t >> 6;
#pragma unroll
    for (int i = 0; i < 16; ++i) {
        int cl = q + i * 4;
        int s = s0 + a;
        tile[cl][a] = (s < S) ? f2b(in[((size_t)b * C + c0 + cl) * S + s]) : f2b(0.f);
    }
    __syncthreads();
#pragma unroll
    for (int i = 0; i < 16; ++i) {
        int sl = q + i * 4;
        int s = s0 + sl;
        if (s < S) {
            int y = s / W, x = s - (s / W) * W;
            out[(((size_t)b * HP + y + pad) * WP + x + pad) * C + c0 + a] = tile[a][sl];
        }
    }
}

// ---------------- zero the 1-px halo of a padded NHWC buffer ----------------
__global__ __launch_bounds__(256) void halo_zero(bf16* __restrict__ buf, int W, int C)
{
    const int b = blockIdx.x, y = blockIdx.y;
    const int P = W + 2;
    const bf16 z = f2b(0.f);
    bf16* row = buf + ((size_t)b * P + y) * P * C;
    if (y == 0 || y == P - 1) {
        for (int i = threadIdx.x; i < P * C; i += 256) row[i] = z;
    } else {
        for (int i = threadIdx.x; i < 2 * C; i += 256) {
            const int x = (i < C) ? 0 : P - 1;
            const int c = (i < C) ? i : i - C;
            row[(size_t)x * C + c] = z;
        }
    }
}

// ---------------- pack NHWC bf16 halves -> NCHW f32 concat output ----------------
__global__ __launch_bounds__(256) void pack_out(const bf16* __restrict__ x1o,
                                                const bf16* __restrict__ x2o,
                                                float* __restrict__ out)
{
    __shared__ bf16 tile[64][68];
    const int b = blockIdx.x, s0 = blockIdx.y * 64, ch0 = blockIdx.z * 64;
    const bf16* src = (ch0 < 512) ? x1o : x2o;
    const int c0 = ch0 & 511;
    const int t = threadIdx.x;
    const int a = t & 63, q = t >> 6;
#pragma unroll
    for (int i = 0; i < 16; ++i) {
        int sl = q + i * 4;
        tile[sl][a] = src[((size_t)b * 1600 + s0 + sl) * 512 + c0 + a];
    }
    __syncthreads();
#pragma unroll
    for (int i = 0; i < 16; ++i) {
        int cl = q + i * 4;
        out[((size_t)b * 1024 + ch0 + cl) * 1600 + s0 + a] = b2f(tile[a][cl]);
    }
}

// ------- weight reorder+convert: w[o][c][ky][kx] f32 -> wr[o][(ky*3+kx)*C + c] bf16 -------
__global__ __launch_bounds__(256) void reorder_w(const float* __restrict__ w,
                                                 bf16* __restrict__ wr,
                                                 int C, int total)
{
    int i = blockIdx.x * 256 + threadIdx.x;
    if (i >= total) return;
    int nineC = 9 * C;
    int o = i / nineC;
    int r = i - o * nineC;
    int tap = r / C;
    int c = r - tap * C;
    wr[i] = f2b(w[((size_t)o * C + c) * 9 + tap]);
}

// ---------------- plain f32 -> bf16 convert ----------------
__global__ __launch_bounds__(256) void f32_to_bf16(const float* __restrict__ in,
                                                   bf16* __restrict__ out, int n)
{
    int i = blockIdx.x * 256 + threadIdx.x;
    if (i < n) out[i] = f2b(in[i]);
}

// ---------------- patch mean pool: x2 NHWC -> kp[b*100][512] bf16 ----------------
__global__ __launch_bounds__(256) void pool_kp(const bf16* __restrict__ x2n,
                                               bf16* __restrict__ kp)
{
    const int p = blockIdx.x;            // b*100 + l
    const int b = p / 100, l = p - (p / 100) * 100;
    const int ph = l / 10, pw = l - (l / 10) * 10;
    const int t = threadIdx.x;           // 256 threads, 2 channels each
    const bf16x2* base = (const bf16x2*)(x2n + (((size_t)(b * 40 + ph * 4) * 40) + pw * 4) * 512) + t;
    float sx = 0.f, sy = 0.f;
#pragma unroll
    for (int py = 0; py < 4; ++py)
#pragma unroll
        for (int px = 0; px < 4; ++px) {
            float2 v = __bfloat1622float2(base[(py * 40 + px) * 256]);
            sx += v.x; sy += v.y;
        }
    ((bf16x2*)(kp + (size_t)p * 512))[t] = __float22bfloat162_rn(make_float2(sx * 0.0625f, sy * 0.0625f));
}

// ---------------- channel-attention MLP at 20x20 source resolution ----------------
__global__ __launch_bounds__(256) void ca_mlp(const bf16* __restrict__ x1n,
                                              const float* __restrict__ w1, const float* __restrict__ b1,
                                              const float* __restrict__ w2, const float* __restrict__ b2,
                                              bf16* __restrict__ xca)
{
    __shared__ float a1v[256];
    __shared__ float part[4][64];
    __shared__ float hid[64];
    const int blk = blockIdx.x;
    const int b = blk / 400;
    const int rem = blk - b * 400;
    const int y = rem / 20, x = rem - (rem / 20) * 20;
    const int t = threadIdx.x;
    const bf16* src = x1n + ((size_t)(b * 22 + y + 1) * 22 + x + 1) * 512 + 256;
    a1v[t] = b2f(src[t]);
    __syncthreads();
    {
        const int h = t & 63, seg = t >> 6;
        float acc = 0.f;
        const float* wp = w1 + (size_t)h * 256 + seg * 64;
        const float* ap = a1v + seg * 64;
#pragma unroll 8
        for (int c = 0; c < 64; ++c) acc += wp[c] * ap[c];
        part[seg][h] = acc;
    }
    __syncthreads();
    if (t < 64)
        hid[t] = fmaxf(part[0][t] + part[1][t] + part[2][t] + part[3][t] + b1[t], 0.f);
    __syncthreads();
    float acc2 = b2[t];
    const float* w2p = w2 + (size_t)t * 64;
#pragma unroll 8
    for (int h = 0; h < 64; ++h) acc2 += w2p[h] * hid[h];
    const float g = 1.f / (1.f + __expf(-acc2));
    const bf16 o = f2b(a1v[t] * g);
    const size_t obase = ((size_t)(b * 42 + 2 * y + 1) * 42 + 2 * x + 1) * 256 + t;
    xca[obase] = o;
    xca[obase + 256] = o;
    xca[obase + 42 * 256] = o;
    xca[obase + 42 * 256 + 256] = o;
}

// ---------------- attention: one block per (batch,head) ----------------
__global__ __launch_bounds__(256, 1)
void attn_kernel(const float* __restrict__ q, const float* __restrict__ k,
                 const bf16* __restrict__ x2n, bf16* __restrict__ attn)
{
    __shared__ float sc[100][100];
    __shared__ bf16 wT[100][104];   // wT[l][ql]
    const int t = threadIdx.x;
    const int n = blockIdx.x;
    const int b = n >> 3, hd = n & 7;
    const float* qn = q + (size_t)n * 3200;
    const float* kn = k + (size_t)n * 3200;
    for (int e = t; e < 10000; e += 256) {
        const int i = e / 100;
        const int j = e - i * 100;
        const float4* qa = (const float4*)(qn + i * 32);
        const float4* ka = (const float4*)(kn + j * 32);
        float d = 0.f;
#pragma unroll
        for (int u = 0; u < 8; ++u) {
            float4 xv = qa[u], yv = ka[u];
            d += xv.x * yv.x + xv.y * yv.y + xv.z * yv.z + xv.w * yv.w;
        }
        sc[i][j] = d * 0.17677669529663687f;   // 1/sqrt(32)
    }
    __syncthreads();
    if (t < 100) {
        float mx = -1e30f;
        for (int j = 0; j < 100; ++j) mx = fmaxf(mx, sc[t][j]);
        float s = 0.f;
        for (int j = 0; j < 100; ++j) s += __expf(sc[t][j] - mx);
        const float inv = 1.f / s;
        for (int j = 0; j < 100; ++j) wT[j][t] = f2b(__expf(sc[t][j] - mx) * inv);
    }
    __syncthreads();
    const int ch0 = (t & 15) * 4;
    const int pix = t >> 4;
    const int py = pix >> 2, px = pix & 3;
    const bf16* vbase = x2n + (((size_t)(b * 40 + py) * 40) + px) * 512 + hd * 64 + ch0;
    for (int ql0 = 0; ql0 < 100; ql0 += 20) {
        float2 a0[20], a1[20];
#pragma unroll
        for (int i = 0; i < 20; ++i) { a0[i] = make_float2(0.f, 0.f); a1[i] = make_float2(0.f, 0.f); }
        for (int l = 0; l < 100; ++l) {
            const int ph = l / 10, pw = l - (l / 10) * 10;
            const bf16* vp = vbase + ((size_t)(ph * 160 + pw * 4)) * 512;
            const float2 v01 = __bfloat1622float2(*(const bf16x2*)vp);
            const float2 v23 = __bfloat1622float2(*(const bf16x2*)(vp + 2));
            const bf16x2* wp = (const bf16x2*)&wT[l][ql0];
#pragma unroll
            for (int ii = 0; ii < 10; ++ii) {
                const float2 w2 = __bfloat1622float2(wp[ii]);
                a0[ii * 2 + 0].x += w2.x * v01.x; a0[ii * 2 + 0].y += w2.x * v01.y;
                a1[ii * 2 + 0].x += w2.x * v23.x; a1[ii * 2 + 0].y += w2.x * v23.y;
                a0[ii * 2 + 1].x += w2.y * v01.x; a0[ii * 2 + 1].y += w2.y * v01.y;
                a1[ii * 2 + 1].x += w2.y * v23.x; a1[ii * 2 + 1].y += w2.y * v23.y;
            }
        }
#pragma unroll
        for (int i = 0; i < 20; ++i) {
            const int ql = ql0 + i;
            const int ph = ql / 10, pw = ql - (ql / 10) * 10;
            bf16* op = attn + (((size_t)(b * 42 + ph * 4 + py + 1) * 42) + pw * 4 + px + 1) * 512 + hd * 64 + ch0;
            *(bf16x2*)op = __float22bfloat162_rn(a0[i]);
            *(bf16x2*)(op + 2) = __float22bfloat162_rn(a1[i]);
        }
    }
}

enum ConvMode { M_QCONV = 0, M_SA1 = 1, M_SA2 = 2, M_C3 = 3, M_CONV2 = 4, M_KPROJ = 5 };

// ---------------- small-M implicit-GEMM MFMA conv (128x128 tile) for QCONV/KPROJ ----------------
template <int MODE>
__global__ __launch_bounds__(256, 2)
void conv_mfma(const bf16* __restrict__ in, const bf16* __restrict__ wr,
               const float* __restrict__ scale, const float* __restrict__ bias,
               float* __restrict__ outf)
{
    constexpr int CIN  = 512;
    constexpr int TAPS = (MODE == M_KPROJ) ? 1 : 9;
    constexpr int STR  = 2;
    constexpr int HP   = 22;
    constexpr int WOUT = 10;
    constexpr int K    = TAPS * CIN;
    constexpr int KD   = (TAPS == 9) ? 3 : 1;

    __shared__ bf16 Al[128][64];
    __shared__ bf16 Bl[128][64];

    const int t = threadIdx.x;
    const int p0 = blockIdx.x * 128;
    const int n0 = blockIdx.y * 128;

    int s_row[4], s_dst8[4], s_src8[4], s_b[4], s_oy[4], s_ox[4];
    const bf16* bB[4];
#pragma unroll
    for (int i = 0; i < 4; ++i) {
        const int task = t + i * 256;
        const int row = task >> 3, chk = task & 7;
        s_row[i] = row;
        s_dst8[i] = chk * 8;
        s_src8[i] = (chk ^ (row & 7)) * 8;
        const int p = p0 + row;
        const int bb = p / 100;
        const int s = p - bb * 100;
        s_b[i] = bb;
        s_oy[i] = s / WOUT;
        s_ox[i] = s - s_oy[i] * WOUT;
        bB[i] = wr + (size_t)(n0 + row) * K + s_src8[i];
    }

    const bf16* aP1[4];
    if (MODE == M_KPROJ) {
#pragma unroll
        for (int i = 0; i < 4; ++i)
            aP1[i] = in + (size_t)(p0 + s_row[i]) * 512 + s_src8[i];
    }

    const int lane = t & 63;
    const int wv = t >> 6;
    const int m_off = (wv >> 1) * 64;
    const int n_off = (wv & 1) * 64;
    const int fr = lane & 15;
    const int qd = lane >> 4;
    const int xa = (fr & 7) << 4;

    f32x4 acc[4][4];
#pragma unroll
    for (int mi = 0; mi < 4; ++mi)
#pragma unroll
        for (int ni = 0; ni < 4; ++ni)
            acc[mi][ni] = (f32x4){0.f, 0.f, 0.f, 0.f};

    for (int ky = 0; ky < KD; ++ky)
    for (int kx = 0; kx < KD; ++kx) {
        const bf16* aT[4];
        if (TAPS == 9) {
#pragma unroll
            for (int i = 0; i < 4; ++i)
                aT[i] = in + ((size_t)((s_b[i] * HP + s_oy[i] * STR + ky) * HP) + s_ox[i] * STR + kx) * CIN + s_src8[i];
        }
        const int kk0 = (ky * KD + kx) * CIN;
        for (int c0 = 0; c0 < CIN; c0 += 64) {
#pragma unroll
            for (int i = 0; i < 4; ++i) {
                const bf16* sa = (MODE == M_KPROJ) ? (aP1[i] + c0) : (aT[i] + c0);
                gload_lds16(sa, &Al[s_row[i]][s_dst8[i]]);
            }
#pragma unroll
            for (int i = 0; i < 4; ++i)
                gload_lds16(bB[i] + (kk0 + c0), &Bl[s_row[i]][s_dst8[i]]);
            __syncthreads();
#pragma unroll
            for (int ks = 0; ks < 2; ++ks) {
                short8 af[4], bfr[4];
                const int coff = (ks * 64 + qd * 16) ^ xa;
#pragma unroll
                for (int mi = 0; mi < 4; ++mi)
                    af[mi] = *(const short8*)((const char*)&Al[m_off + mi * 16 + fr][0] + coff);
#pragma unroll
                for (int ni = 0; ni < 4; ++ni)
                    bfr[ni] = *(const short8*)((const char*)&Bl[n_off + ni * 16 + fr][0] + coff);
#pragma unroll
                for (int mi = 0; mi < 4; ++mi)
#pragma unroll
                    for (int ni = 0; ni < 4; ++ni)
                        acc[mi][ni] = __builtin_amdgcn_mfma_f32_16x16x32_bf16(af[mi], bfr[ni], acc[mi][ni], 0, 0, 0);
            }
            __syncthreads();
        }
    }

#pragma unroll
    for (int ni = 0; ni < 4; ++ni) {
        const int nn = n0 + n_off + ni * 16 + fr;
        float scv = 1.f, bsv = 0.f;
        if (MODE != M_KPROJ) { scv = scale[nn]; bsv = bias[nn]; }
#pragma unroll
        for (int mi = 0; mi < 4; ++mi) {
            const int mb = p0 + m_off + mi * 16 + qd * 4;
#pragma unroll
            for (int r = 0; r < 4; ++r) {
                const int p = mb + r;
                const float v = acc[mi][ni][r];
                const int bb = p / 100, l = p - (p / 100) * 100;
                if (MODE == M_KPROJ) {
                    outf[(((size_t)(bb * 8 + (nn >> 5))) * 100 + l) * 32 + (nn & 31)] = v;
                } else {
                    const float y = v * scv + bsv;
                    const float a = y / (1.f + __expf(-y));
                    outf[(((size_t)(bb * 8 + (nn >> 5))) * 100 + l) * 32 + (nn & 31)] = a;
                }
            }
        }
    }
}

// ---------------- big-M conv body: 256x256 tile, 512 threads, 2-phase counted-vmcnt pipeline ----------------
template <int MODE>
__device__ __forceinline__ void conv_body256(
    const bf16* __restrict__ in, const bf16* __restrict__ in2,
    const bf16* __restrict__ wr, const float* __restrict__ scale,
    const float* __restrict__ bias, const bf16* __restrict__ resid,
    bf16* __restrict__ outb, bf16* lA, bf16* lB,
    int mtile, int ntile)
{
    constexpr int CIN  = (MODE == M_C3) ? 512 : (MODE == M_CONV2 ? 768 : 256);
    constexpr int TAPS = (MODE == M_CONV2) ? 1 : 9;
    constexpr int K    = TAPS * CIN;
    constexpr int NT   = K / 64;
    constexpr int CPT  = CIN / 64;
    constexpr int L2C  = (CPT == 8) ? 3 : 2;
    constexpr int HP   = 42;

    const int t = threadIdx.x;
    const int p0 = mtile * 256;
    const int n0 = ntile * 256;

    const int row64 = t >> 3;
    const int chk = t & 7;
    const int src8 = (chk ^ (row64 & 7)) * 8;   // pre-swizzled global chunk
    const int dst8 = chk * 8;                   // linear LDS chunk

    const bf16* aBase[4];
    const bf16* aBase2[4];
#pragma unroll
    for (int si = 0; si < 4; ++si) {
        const int p = p0 + si * 64 + row64;
        const int b = p / 1600;
        const int s = p - b * 1600;
        const int oy = s / 40, ox = s - (s / 40) * 40;
        if (MODE == M_CONV2) {
            aBase[si]  = in  + ((size_t)(b * 22 + (oy >> 1) + 1) * 22 + (ox >> 1) + 1) * 512 + src8;
            aBase2[si] = in2 + ((size_t)(b * 1600 + oy * 40 + ox)) * 256 + src8;
        } else {
            aBase[si]  = in  + ((size_t)(b * HP + oy) * HP + ox) * CIN + src8;
            aBase2[si] = nullptr;
        }
    }
    const bf16* bBase[4];
#pragma unroll
    for (int si = 0; si < 4; ++si)
        bBase[si] = wr + (size_t)(n0 + si * 64 + row64) * K + src8;

    const int lane = t & 63;
    const int wv = t >> 6;
    const int m_off = (wv >> 2) * 128;      // 2 wave-rows
    const int n_off = (wv & 3) * 64;        // 4 wave-cols
    const int fr = lane & 15;
    const int qd = lane >> 4;
    const int xa = (fr & 7) << 4;

    f32x4 acc[8][4];
#pragma unroll
    for (int mi = 0; mi < 8; ++mi)
#pragma unroll
        for (int ni = 0; ni < 4; ++ni)
            acc[mi][ni] = (f32x4){0.f, 0.f, 0.f, 0.f};

#define LDA8(buf, rrow, kkk) \
    (*(const short8*)((const char*)lA + (buf) * 32768 + (rrow) * 128 + ((((kkk) * 64) + qd * 16) ^ xa)))
#define LDB8(buf, rrow, kkk) \
    (*(const short8*)((const char*)lB + (buf) * 32768 + (rrow) * 128 + ((((kkk) * 64) + qd * 16) ^ xa)))

    // ---- prologue: stage K-tile 0 fully into buffer 0 ----
#pragma unroll
    for (int si = 0; si < 4; ++si)
        gload_lds16(aBase[si], lA + (si * 64 + row64) * 64 + dst8);
#pragma unroll
    for (int si = 0; si < 4; ++si)
        gload_lds16(bBase[si], lB + (si * 64 + row64) * 64 + dst8);
    asm volatile("s_waitcnt vmcnt(0)" ::: "memory");
    __syncthreads();

#pragma clang loop unroll(disable)
    for (int kt = 0; kt < NT; ++kt) {
        const int cur = kt & 1;
        const int nxt = cur ^ 1;
        const int ktn = kt + 1;
        const bool pf = (ktn < NT);
        int offAn = 0, c0n = 0;
        if (pf) {
            if (MODE == M_CONV2) {
                c0n = ktn * 64;
            } else {
                const int tap = ktn >> L2C;
                const int ci = ktn & (CPT - 1);
                const int ky = tap / 3, kx = tap - ky * 3;
                offAn = (ky * HP + kx) * CIN + ci * 64;
            }
        }
        const int offBn = ktn * 64;

        auto stA = [&](int si) {
            const bf16* sa;
            if (MODE == M_CONV2) sa = (c0n < 512) ? (aBase[si] + c0n) : (aBase2[si] + (c0n - 512));
            else sa = aBase[si] + offAn;
            gload_lds16(sa, lA + nxt * 16384 + (si * 64 + row64) * 64 + dst8);
        };
        auto stB = [&](int si) {
            gload_lds16(bBase[si] + offBn, lB + nxt * 16384 + (si * 64 + row64) * 64 + dst8);
        };

        short8 af[4][2], bfr[4][2];

        // ===== phase A: read A-h0 + B-all; issue {a0,a2,b0,b1}; MFMA acc[0..3][0..3] =====
#pragma unroll
        for (int m4 = 0; m4 < 4; ++m4) {
            af[m4][0] = LDA8(cur, m_off + m4 * 16 + fr, 0);
            af[m4][1] = LDA8(cur, m_off + m4 * 16 + fr, 1);
        }
#pragma unroll
        for (int n4 = 0; n4 < 4; ++n4) {
            bfr[n4][0] = LDB8(cur, n_off + n4 * 16 + fr, 0);
            bfr[n4][1] = LDB8(cur, n_off + n4 * 16 + fr, 1);
        }
        if (pf) { stA(0); stA(2); stB(0); stB(1); }
        PH_BAR();
        WAIT_LGKM0();
        __builtin_amdgcn_s_setprio(1);
#pragma unroll
        for (int m4 = 0; m4 < 4; ++m4)
#pragma unroll
            for (int n4 = 0; n4 < 4; ++n4) {
                acc[m4][n4] = __builtin_amdgcn_mfma_f32_16x16x32_bf16(af[m4][0], bfr[n4][0], acc[m4][n4], 0, 0, 0);
                acc[m4][n4] = __builtin_amdgcn_mfma_f32_16x16x32_bf16(af[m4][1], bfr[n4][1], acc[m4][n4], 0, 0, 0);
            }
        __builtin_amdgcn_s_setprio(0);
        // wait for the cross-tile A-h1 loads (oldest 2) before phase B reads them
        if (pf) { WAIT_VM4(); } else { WAIT_VM0(); }
        PH_BAR();

        // ===== phase B: read A-h1; issue {b2,b3,a1,a3}; MFMA acc[4..7][0..3] =====
#pragma unroll
        for (int m4 = 0; m4 < 4; ++m4) {
            af[m4][0] = LDA8(cur, m_off + (4 + m4) * 16 + fr, 0);
            af[m4][1] = LDA8(cur, m_off + (4 + m4) * 16 + fr, 1);
        }
        if (pf) { stB(2); stB(3); stA(1); stA(3); }
        PH_BAR();
        WAIT_LGKM0();
        __builtin_amdgcn_s_setprio(1);
#pragma unroll
        for (int m4 = 0; m4 < 4; ++m4)
#pragma unroll
            for (int n4 = 0; n4 < 4; ++n4) {
                acc[4 + m4][n4] = __builtin_amdgcn_mfma_f32_16x16x32_bf16(af[m4][0], bfr[n4][0], acc[4 + m4][n4], 0, 0, 0);
                acc[4 + m4][n4] = __builtin_amdgcn_mfma_f32_16x16x32_bf16(af[m4][1], bfr[n4][1], acc[4 + m4][n4], 0, 0, 0);
            }
        __builtin_amdgcn_s_setprio(0);
        // counted: leave the 2 newest (a1,a3 of nxt) in flight across the tile boundary
        if (pf) { WAIT_VM2(); }
        PH_BAR();
    }
#undef LDA8
#undef LDB8

    // ---- epilogue ----
#pragma unroll
    for (int ni = 0; ni < 4; ++ni) {
        const int nn = n0 + n_off + ni * 16 + fr;
        const float scv = scale[nn];
        const float bsv = bias[nn];
#pragma unroll
        for (int mi = 0; mi < 8; ++mi) {
            const int mb = p0 + m_off + mi * 16 + qd * 4;
#pragma unroll
            for (int r = 0; r < 4; ++r) {
                const int p = mb + r;
                const float y = acc[mi][ni][r] * scv + bsv;
                const float a = y / (1.f + __expf(-y));
                if (MODE == M_SA1) {
                    const int bb = p / 1600; const int s = p - bb * 1600;
                    const int oy = s / 40, ox = s - (s / 40) * 40;
                    outb[(((size_t)(bb * 42 + oy + 1)) * 42 + ox + 1) * 256 + nn] = f2b(a);
                } else if (MODE == M_SA2) {
                    const int bb = p / 1600; const int s = p - bb * 1600;
                    const int oy = s / 40, ox = s - (s / 40) * 40;
                    const size_t roff = (((size_t)(bb * 42 + oy + 1)) * 42 + ox + 1) * 256 + nn;
                    outb[(size_t)p * 256 + nn] = f2b(a + b2f(resid[roff]));
                } else if (MODE == M_C3) {
                    const int bb = p / 1600; const int s = p - bb * 1600;
                    const int oy = s / 40, ox = s - (s / 40) * 40;
                    const size_t roff = (((size_t)(bb * 42 + oy + 1)) * 42 + ox + 1) * 512 + nn;
                    outb[(size_t)p * 512 + nn] = f2b(a + b2f(resid[roff]));
                } else { // M_CONV2
                    outb[(size_t)p * 512 + nn] = f2b(a);
                }
            }
        }
    }
}

// single-mode wrapper (SA2: 200 blocks, CONV2: 400 blocks)
template <int MODE>
__global__ __launch_bounds__(512, 2)
void conv_mfma256(const bf16* __restrict__ in, const bf16* __restrict__ in2,
                  const bf16* __restrict__ wr,
                  const float* __restrict__ scale, const float* __restrict__ bias,
                  const bf16* __restrict__ resid,
                  bf16* __restrict__ outb)
{
    __shared__ bf16 Al[2][256][64];
    __shared__ bf16 Bl[2][256][64];
    int mtile, ntile;
    if (MODE == M_CONV2 || MODE == M_C3) { mtile = blockIdx.x >> 1; ntile = blockIdx.x & 1; }
    else { mtile = blockIdx.x; ntile = 0; }
    conv_body256<MODE>(in, in2, wr, scale, bias, resid, outb,
                       &Al[0][0][0], &Bl[0][0][0], mtile, ntile);
}

// merged C3 + SA1 launch: C3 (long blocks) first for LPT dispatch, SA1 backfills
__global__ __launch_bounds__(512, 2)
void conv_c3_sa1(const bf16* __restrict__ attn, const bf16* __restrict__ wc3,
                 const float* __restrict__ c3_s, const float* __restrict__ c3_b,
                 bf16* __restrict__ x2o,
                 const bf16* __restrict__ xca, const bf16* __restrict__ wsa1,
                 const float* __restrict__ sa1_s, const float* __restrict__ sa1_b,
                 bf16* __restrict__ tbuf)
{
    __shared__ bf16 Al[2][256][64];
    __shared__ bf16 Bl[2][256][64];
    const int bx = blockIdx.x;
    if (bx < 400) {
        conv_body256<M_C3>(attn, nullptr, wc3, c3_s, c3_b, attn, x2o,
                           &Al[0][0][0], &Bl[0][0][0], bx >> 1, bx & 1);
    } else {
        conv_body256<M_SA1>(xca, nullptr, wsa1, sa1_s, sa1_b, nullptr, tbuf,
                            &Al[0][0][0], &Bl[0][0][0], bx - 400, 0);
    }
}

extern "C" void kernel_launch(void* const* d_in, const int* in_sizes, int n_in,
                              void* d_out, int out_size, void* d_ws, size_t ws_size,
                              hipStream_t stream)
{
    const float* x1      = (const float*)d_in[0];
    const float* x2      = (const float*)d_in[1];
    const float* q_w     = (const float*)d_in[2];
    const float* q_s     = (const float*)d_in[3];
    const float* q_b     = (const float*)d_in[4];
    const float* key_w   = (const float*)d_in[5];
    const float* ca_w1   = (const float*)d_in[6];
    const float* ca_b1   = (const float*)d_in[7];
    const float* ca_w2   = (const float*)d_in[8];
    const float* ca_b2   = (const float*)d_in[9];
    const float* sa1_w   = (const float*)d_in[10];
    const float* sa1_s   = (const float*)d_in[11];
    const float* sa1_b   = (const float*)d_in[12];
    const float* sa2_w   = (const float*)d_in[13];
    const float* sa2_s   = (const float*)d_in[14];
    const float* sa2_b   = (const float*)d_in[15];
    const float* conv2_w = (const float*)d_in[16];
    const float* conv2_s = (const float*)d_in[17];
    const float* conv2_b = (const float*)d_in[18];
    const float* c3_w    = (const float*)d_in[19];
    const float* c3_s    = (const float*)d_in[20];
    const float* c3_b    = (const float*)d_in[21];

    char* ws = (char*)d_ws;
    // workspace layout (bytes) — padded NHWC buffers, aggressive aliasing; peak 213,254,144
    const size_t o_x1n  = 0;                 // 32*22*22*512 bf16 : 15,859,712 (halo)
    const size_t o_x2n  = 15859712;          // 32*1600*512 bf16  : 52,428,800 (x2o alias after attn)
    const size_t o_attn = 68288512;          // 32*42*42*512 bf16 : 57,802,752 (halo; x1o alias after C3)
    const size_t o_xca  = 126091264;         // 32*42*42*256 bf16 : 28,901,376 (halo; live through SA2)
    const size_t o_tbuf = 154992640;         // 32*42*42*256 bf16 : 28,901,376 (halo; k/q/wkey alias before SA1)
    const size_t o_a2   = 183894016;         // 32*1600*256 bf16  : 26,214,400 (kp/wq/wc3 alias before SA2)
    const size_t o_ws1  = 210108416;         // 256*2304 bf16 : 1,179,648
    const size_t o_ws2  = 211288064;         // 256*2304 bf16 : 1,179,648
    const size_t o_wc2  = 212467712;         // 512*768  bf16 :   786,432
    // aliases
    const size_t o_k    = o_tbuf;            // 3,276,800 f32
    const size_t o_q    = o_tbuf + 3276800;  // 3,276,800 f32
    const size_t o_wkey = o_tbuf + 6553600;  //   262,144 bf16
    const size_t o_kp   = o_a2;              // 3,276,800 bf16
    const size_t o_wq   = o_a2 + 3276800;    // 2,359,296 bf16
    const size_t o_wc3  = o_a2 + 5636096;    // 4,718,592 bf16 (dead before SA2 writes a2)

    bf16*  x1n    = (bf16*)(ws + o_x1n);
    bf16*  x2n    = (bf16*)(ws + o_x2n);
    float* k_attn = (float*)(ws + o_k);
    float* q_attn = (float*)(ws + o_q);
    bf16*  attn   = (bf16*)(ws + o_attn);
    bf16*  xca    = (bf16*)(ws + o_xca);
    bf16*  tbuf   = (bf16*)(ws + o_tbuf);
    bf16*  a2     = (bf16*)(ws + o_a2);
    bf16*  wq     = (bf16*)(ws + o_wq);
    bf16*  wc3    = (bf16*)(ws + o_wc3);
    bf16*  wsa1   = (bf16*)(ws + o_ws1);
    bf16*  wsa2   = (bf16*)(ws + o_ws2);
    bf16*  kp     = (bf16*)(ws + o_kp);
    bf16*  wkey   = (bf16*)(ws + o_wkey);
    bf16*  wc2    = (bf16*)(ws + o_wc2);
    bf16*  x2o    = (bf16*)(ws + o_x2n);     // alias: x2n dead after attn_kernel
    bf16*  x1o    = (bf16*)(ws + o_attn);    // alias: attn dead after C3

    const dim3 blk(256);
    const dim3 blk512(512);

    halo_zero<<<dim3(32, 22), blk, 0, stream>>>(x1n, 20, 512);
    halo_zero<<<dim3(32, 42), blk, 0, stream>>>(xca, 40, 256);
    halo_zero<<<dim3(32, 42), blk, 0, stream>>>(attn, 40, 512);

    nchw_to_nhwc<<<dim3(32, 7, 8), blk, 0, stream>>>(x1, x1n, 512, 20, 20, 1);
    nchw_to_nhwc<<<dim3(32, 25, 8), blk, 0, stream>>>(x2, x2n, 512, 40, 40, 0);
    reorder_w<<<4608, blk, 0, stream>>>(q_w,  wq,   512, 256 * 512 * 9);
    reorder_w<<<9216, blk, 0, stream>>>(c3_w, wc3,  512, 512 * 512 * 9);
    reorder_w<<<2304, blk, 0, stream>>>(sa1_w, wsa1, 256, 256 * 256 * 9);
    reorder_w<<<2304, blk, 0, stream>>>(sa2_w, wsa2, 256, 256 * 256 * 9);
    f32_to_bf16<<<512, blk, 0, stream>>>(key_w, wkey, 256 * 512);
    f32_to_bf16<<<1536, blk, 0, stream>>>(conv2_w, wc2, 512 * 768);
    pool_kp<<<3200, blk, 0, stream>>>(x2n, kp);

    conv_mfma<M_KPROJ><<<dim3(25, 2), blk, 0, stream>>>(kp, wkey, nullptr, nullptr, k_attn);
    conv_mfma<M_QCONV><<<dim3(25, 2), blk, 0, stream>>>(x1n, wq, q_s, q_b, q_attn);

    attn_kernel<<<256, blk, 0, stream>>>(q_attn, k_attn, x2n, attn);

    // k/q/wkey dead now; zero tbuf halo before SA1 writes into it
    halo_zero<<<dim3(32, 42), blk, 0, stream>>>(tbuf, 40, 256);

    ca_mlp<<<12800, blk, 0, stream>>>(x1n, ca_w1, ca_b1, ca_w2, ca_b2, xca);

    // merged: C3 (blocks 0-399) + SA1 (blocks 400-599) — independent, LPT-balanced
    conv_c3_sa1<<<600, blk512, 0, stream>>>(attn, wc3, c3_s, c3_b, x2o,
                                            xca, wsa1, sa1_s, sa1_b, tbuf);

    conv_mfma256<M_SA2><<<200, blk512, 0, stream>>>(tbuf, nullptr, wsa2,
        sa2_s, sa2_b, xca, a2);
    conv_mfma256<M_CONV2><<<400, blk512, 0, stream>>>(x1n, a2, wc2,
        conv2_s, conv2_b, nullptr, x1o);

    pack_out<<<dim3(32, 25, 16), blk, 0, stream>>>(x1o, x2o, (float*)d_out);

    (void)in_sizes; (void)n_in; (void)out_size; (void)ws_size;
}

// Round 5
// 1422.190 us; speedup vs baseline: 1.0357x; 1.0035x over previous
//
#include <hip/hip_runtime.h>
#include <hip/hip_bf16.h>

using bf16 = __hip_bfloat16;
using bf16x2 = __hip_bfloat162;
typedef __attribute__((ext_vector_type(8))) short short8;
typedef __attribute__((ext_vector_type(4))) float f32x4;

__device__ __forceinline__ float b2f(bf16 v) { return __bfloat162float(v); }
__device__ __forceinline__ bf16 f2b(float v) { return __float2bfloat16(v); }

// async global->LDS, 16B per lane; dest must be wave-uniform base + lane*16
__device__ __forceinline__ void gload_lds16(const bf16* g, bf16* l)
{
    __builtin_amdgcn_global_load_lds(
        (const __attribute__((address_space(1))) void*)g,
        (__attribute__((address_space(3))) void*)l,
        16, 0, 0);
}

#define PH_BAR() do { __builtin_amdgcn_sched_barrier(0); __builtin_amdgcn_s_barrier(); __builtin_amdgcn_sched_barrier(0); } while (0)
#define WAIT_LGKM0() do { asm volatile("s_waitcnt lgkmcnt(0)" ::: "memory"); __builtin_amdgcn_sched_barrier(0); } while (0)
#define WAIT_VM0() do { asm volatile("s_waitcnt vmcnt(0)" ::: "memory"); __builtin_amdgcn_sched_barrier(0); } while (0)
#define WAIT_VM2() do { asm volatile("s_waitcnt vmcnt(2)" ::: "memory"); __builtin_amdgcn_sched_barrier(0); } while (0)
#define WAIT_VM6() do { asm volatile("s_waitcnt vmcnt(6)" ::: "memory"); __builtin_amdgcn_sched_barrier(0); } while (0)

// ---------------- NCHW f32 -> NHWC bf16 transpose (optionally halo-padded out) ----------------
__global__ __launch_bounds__(256) void nchw_to_nhwc(const float* __restrict__ in,
                                                    bf16* __restrict__ out,
                                                    int C, int H, int W, int pad)
{
    __shared__ bf16 tile[64][68];
    const int S = H * W;
    const int HP = H + 2 * pad, WP = W + 2 * pad;
    const int b = blockIdx.x, s0 = blockIdx.y * 64, c0 = blockIdx.z * 64;
    const int t = threadIdx.x;
    const int a = t & 63, q = t >> 6;
#pragma unroll
    for (int i = 0; i < 16; ++i) {
        int cl = q + i * 4;
        int s = s0 + a;
        tile[cl][a] = (s < S) ? f2b(in[((size_t)b * C + c0 + cl) * S + s]) : f2b(0.f);
    }
    __syncthreads();
#pragma unroll
    for (int i = 0; i < 16; ++i) {
        int sl = q + i * 4;
        int s = s0 + sl;
        if (s < S) {
            int y = s / W, x = s - (s / W) * W;
            out[(((size_t)b * HP + y + pad) * WP + x + pad) * C + c0 + a] = tile[a][sl];
        }
    }
}

// ---------------- zero the 1-px halo of a padded NHWC buffer ----------------
__global__ __launch_bounds__(256) void halo_zero(bf16* __restrict__ buf, int W, int C)
{
    const int b = blockIdx.x, y = blockIdx.y;
    const int P = W + 2;
    const bf16 z = f2b(0.f);
    bf16* row = buf + ((size_t)b * P + y) * P * C;
    if (y == 0 || y == P - 1) {
        for (int i = threadIdx.x; i < P * C; i += 256) row[i] = z;
    } else {
        for (int i = threadIdx.x; i < 2 * C; i += 256) {
            const int x = (i < C) ? 0 : P - 1;
            const int c = (i < C) ? i : i - C;
            row[(size_t)x * C + c] = z;
        }
    }
}

// ---------------- pack NHWC bf16 halves -> NCHW f32 concat output ----------------
__global__ __launch_bounds__(256) void pack_out(const bf16* __restrict__ x1o,
                                                const bf16* __restrict__ x2o,
                                                float* __restrict__ out)
{
    __shared__ bf16 tile[64][68];
    const int b = blockIdx.x, s0 = blockIdx.y * 64, ch0 = blockIdx.z * 64;
    const bf16* src = (ch0 < 512) ? x1o : x2o;
    const int c0 = ch0 & 511;
    const int t = threadIdx.x;
    const int a = t & 63, q = t >> 6;
#pragma unroll
    for (int i = 0; i < 16; ++i) {
        int sl = q + i * 4;
        tile[sl][a] = src[((size_t)b * 1600 + s0 + sl) * 512 + c0 + a];
    }
    __syncthreads();
#pragma unroll
    for (int i = 0; i < 16; ++i) {
        int cl = q + i * 4;
        out[((size_t)b * 1024 + ch0 + cl) * 1600 + s0 + a] = b2f(tile[a][cl]);
    }
}

// ------- weight reorder+convert: w[o][c][ky][kx] f32 -> wr[o][(ky*3+kx)*C + c] bf16 -------
__global__ __launch_bounds__(256) void reorder_w(const float* __restrict__ w,
                                                 bf16* __restrict__ wr,
                                                 int C, int total)
{
    int i = blockIdx.x * 256 + threadIdx.x;
    if (i >= total) return;
    int nineC = 9 * C;
    int o = i / nineC;
    int r = i - o * nineC;
    int tap = r / C;
    int c = r - tap * C;
    wr[i] = f2b(w[((size_t)o * C + c) * 9 + tap]);
}

// ---------------- plain f32 -> bf16 convert ----------------
__global__ __launch_bounds__(256) void f32_to_bf16(const float* __restrict__ in,
                                                   bf16* __restrict__ out, int n)
{
    int i = blockIdx.x * 256 + threadIdx.x;
    if (i < n) out[i] = f2b(in[i]);
}

// ---------------- patch mean pool: x2 NHWC -> kp[b*100][512] bf16 ----------------
__global__ __launch_bounds__(256) void pool_kp(const bf16* __restrict__ x2n,
                                               bf16* __restrict__ kp)
{
    const int p = blockIdx.x;            // b*100 + l
    const int b = p / 100, l = p - (p / 100) * 100;
    const int ph = l / 10, pw = l - (l / 10) * 10;
    const int t = threadIdx.x;           // 256 threads, 2 channels each
    const bf16x2* base = (const bf16x2*)(x2n + (((size_t)(b * 40 + ph * 4) * 40) + pw * 4) * 512) + t;
    float sx = 0.f, sy = 0.f;
#pragma unroll
    for (int py = 0; py < 4; ++py)
#pragma unroll
        for (int px = 0; px < 4; ++px) {
            float2 v = __bfloat1622float2(base[(py * 40 + px) * 256]);
            sx += v.x; sy += v.y;
        }
    ((bf16x2*)(kp + (size_t)p * 512))[t] = __float22bfloat162_rn(make_float2(sx * 0.0625f, sy * 0.0625f));
}

// ---------------- channel-attention MLP at 20x20 source resolution ----------------
__global__ __launch_bounds__(256) void ca_mlp(const bf16* __restrict__ x1n,
                                              const float* __restrict__ w1, const float* __restrict__ b1,
                                              const float* __restrict__ w2, const float* __restrict__ b2,
                                              bf16* __restrict__ xca)
{
    __shared__ float a1v[256];
    __shared__ float part[4][64];
    __shared__ float hid[64];
    const int blk = blockIdx.x;
    const int b = blk / 400;
    const int rem = blk - b * 400;
    const int y = rem / 20, x = rem - (rem / 20) * 20;
    const int t = threadIdx.x;
    const bf16* src = x1n + ((size_t)(b * 22 + y + 1) * 22 + x + 1) * 512 + 256;
    a1v[t] = b2f(src[t]);
    __syncthreads();
    {
        const int h = t & 63, seg = t >> 6;
        float acc = 0.f;
        const float* wp = w1 + (size_t)h * 256 + seg * 64;
        const float* ap = a1v + seg * 64;
#pragma unroll 8
        for (int c = 0; c < 64; ++c) acc += wp[c] * ap[c];
        part[seg][h] = acc;
    }
    __syncthreads();
    if (t < 64)
        hid[t] = fmaxf(part[0][t] + part[1][t] + part[2][t] + part[3][t] + b1[t], 0.f);
    __syncthreads();
    float acc2 = b2[t];
    const float* w2p = w2 + (size_t)t * 64;
#pragma unroll 8
    for (int h = 0; h < 64; ++h) acc2 += w2p[h] * hid[h];
    const float g = 1.f / (1.f + __expf(-acc2));
    const bf16 o = f2b(a1v[t] * g);
    const size_t obase = ((size_t)(b * 42 + 2 * y + 1) * 42 + 2 * x + 1) * 256 + t;
    xca[obase] = o;
    xca[obase + 256] = o;
    xca[obase + 42 * 256] = o;
    xca[obase + 42 * 256 + 256] = o;
}

// ---------------- attention: one block per (batch,head) ----------------
__global__ __launch_bounds__(256, 1)
void attn_kernel(const float* __restrict__ q, const float* __restrict__ k,
                 const bf16* __restrict__ x2n, bf16* __restrict__ attn)
{
    __shared__ float sc[100][100];
    __shared__ bf16 wT[100][104];   // wT[l][ql]
    const int t = threadIdx.x;
    const int n = blockIdx.x;
    const int b = n >> 3, hd = n & 7;
    const float* qn = q + (size_t)n * 3200;
    const float* kn = k + (size_t)n * 3200;
    for (int e = t; e < 10000; e += 256) {
        const int i = e / 100;
        const int j = e - i * 100;
        const float4* qa = (const float4*)(qn + i * 32);
        const float4* ka = (const float4*)(kn + j * 32);
        float d = 0.f;
#pragma unroll
        for (int u = 0; u < 8; ++u) {
            float4 xv = qa[u], yv = ka[u];
            d += xv.x * yv.x + xv.y * yv.y + xv.z * yv.z + xv.w * yv.w;
        }
        sc[i][j] = d * 0.17677669529663687f;   // 1/sqrt(32)
    }
    __syncthreads();
    if (t < 100) {
        float mx = -1e30f;
        for (int j = 0; j < 100; ++j) mx = fmaxf(mx, sc[t][j]);
        float s = 0.f;
        for (int j = 0; j < 100; ++j) s += __expf(sc[t][j] - mx);
        const float inv = 1.f / s;
        for (int j = 0; j < 100; ++j) wT[j][t] = f2b(__expf(sc[t][j] - mx) * inv);
    }
    __syncthreads();
    const int ch0 = (t & 15) * 4;
    const int pix = t >> 4;
    const int py = pix >> 2, px = pix & 3;
    const bf16* vbase = x2n + (((size_t)(b * 40 + py) * 40) + px) * 512 + hd * 64 + ch0;
    for (int ql0 = 0; ql0 < 100; ql0 += 20) {
        float2 a0[20], a1[20];
#pragma unroll
        for (int i = 0; i < 20; ++i) { a0[i] = make_float2(0.f, 0.f); a1[i] = make_float2(0.f, 0.f); }
        for (int l = 0; l < 100; ++l) {
            const int ph = l / 10, pw = l - (l / 10) * 10;
            const bf16* vp = vbase + ((size_t)(ph * 160 + pw * 4)) * 512;
            const float2 v01 = __bfloat1622float2(*(const bf16x2*)vp);
            const float2 v23 = __bfloat1622float2(*(const bf16x2*)(vp + 2));
            const bf16x2* wp = (const bf16x2*)&wT[l][ql0];
#pragma unroll
            for (int ii = 0; ii < 10; ++ii) {
                const float2 w2 = __bfloat1622float2(wp[ii]);
                a0[ii * 2 + 0].x += w2.x * v01.x; a0[ii * 2 + 0].y += w2.x * v01.y;
                a1[ii * 2 + 0].x += w2.x * v23.x; a1[ii * 2 + 0].y += w2.x * v23.y;
                a0[ii * 2 + 1].x += w2.y * v01.x; a0[ii * 2 + 1].y += w2.y * v01.y;
                a1[ii * 2 + 1].x += w2.y * v23.x; a1[ii * 2 + 1].y += w2.y * v23.y;
            }
        }
#pragma unroll
        for (int i = 0; i < 20; ++i) {
            const int ql = ql0 + i;
            const int ph = ql / 10, pw = ql - (ql / 10) * 10;
            bf16* op = attn + (((size_t)(b * 42 + ph * 4 + py + 1) * 42) + pw * 4 + px + 1) * 512 + hd * 64 + ch0;
            *(bf16x2*)op = __float22bfloat162_rn(a0[i]);
            *(bf16x2*)(op + 2) = __float22bfloat162_rn(a1[i]);
        }
    }
}

enum ConvMode { M_QCONV = 0, M_SA1 = 1, M_SA2 = 2, M_C3 = 3, M_CONV2 = 4, M_KPROJ = 5 };

// ---------------- small-M implicit-GEMM MFMA conv (128x128 tile) for QCONV/KPROJ ----------------
template <int MODE>
__global__ __launch_bounds__(256, 2)
void conv_mfma(const bf16* __restrict__ in, const bf16* __restrict__ wr,
               const float* __restrict__ scale, const float* __restrict__ bias,
               float* __restrict__ outf)
{
    constexpr int CIN  = 512;
    constexpr int TAPS = (MODE == M_KPROJ) ? 1 : 9;
    constexpr int STR  = 2;
    constexpr int HP   = 22;
    constexpr int WOUT = 10;
    constexpr int K    = TAPS * CIN;
    constexpr int KD   = (TAPS == 9) ? 3 : 1;

    __shared__ bf16 Al[128][64];
    __shared__ bf16 Bl[128][64];

    const int t = threadIdx.x;
    const int p0 = blockIdx.x * 128;
    const int n0 = blockIdx.y * 128;

    int s_row[4], s_dst8[4], s_src8[4], s_b[4], s_oy[4], s_ox[4];
    const bf16* bB[4];
#pragma unroll
    for (int i = 0; i < 4; ++i) {
        const int task = t + i * 256;
        const int row = task >> 3, chk = task & 7;
        s_row[i] = row;
        s_dst8[i] = chk * 8;
        s_src8[i] = (chk ^ (row & 7)) * 8;
        const int p = p0 + row;
        const int bb = p / 100;
        const int s = p - bb * 100;
        s_b[i] = bb;
        s_oy[i] = s / WOUT;
        s_ox[i] = s - s_oy[i] * WOUT;
        bB[i] = wr + (size_t)(n0 + row) * K + s_src8[i];
    }

    const bf16* aP1[4];
    if (MODE == M_KPROJ) {
#pragma unroll
        for (int i = 0; i < 4; ++i)
            aP1[i] = in + (size_t)(p0 + s_row[i]) * 512 + s_src8[i];
    }

    const int lane = t & 63;
    const int wv = t >> 6;
    const int m_off = (wv >> 1) * 64;
    const int n_off = (wv & 1) * 64;
    const int fr = lane & 15;
    const int qd = lane >> 4;
    const int xa = (fr & 7) << 4;

    f32x4 acc[4][4];
#pragma unroll
    for (int mi = 0; mi < 4; ++mi)
#pragma unroll
        for (int ni = 0; ni < 4; ++ni)
            acc[mi][ni] = (f32x4){0.f, 0.f, 0.f, 0.f};

    for (int ky = 0; ky < KD; ++ky)
    for (int kx = 0; kx < KD; ++kx) {
        const bf16* aT[4];
        if (TAPS == 9) {
#pragma unroll
            for (int i = 0; i < 4; ++i)
                aT[i] = in + ((size_t)((s_b[i] * HP + s_oy[i] * STR + ky) * HP) + s_ox[i] * STR + kx) * CIN + s_src8[i];
        }
        const int kk0 = (ky * KD + kx) * CIN;
        for (int c0 = 0; c0 < CIN; c0 += 64) {
#pragma unroll
            for (int i = 0; i < 4; ++i) {
                const bf16* sa = (MODE == M_KPROJ) ? (aP1[i] + c0) : (aT[i] + c0);
                gload_lds16(sa, &Al[s_row[i]][s_dst8[i]]);
            }
#pragma unroll
            for (int i = 0; i < 4; ++i)
                gload_lds16(bB[i] + (kk0 + c0), &Bl[s_row[i]][s_dst8[i]]);
            __syncthreads();
#pragma unroll
            for (int ks = 0; ks < 2; ++ks) {
                short8 af[4], bfr[4];
                const int coff = (ks * 64 + qd * 16) ^ xa;
#pragma unroll
                for (int mi = 0; mi < 4; ++mi)
                    af[mi] = *(const short8*)((const char*)&Al[m_off + mi * 16 + fr][0] + coff);
#pragma unroll
                for (int ni = 0; ni < 4; ++ni)
                    bfr[ni] = *(const short8*)((const char*)&Bl[n_off + ni * 16 + fr][0] + coff);
#pragma unroll
                for (int mi = 0; mi < 4; ++mi)
#pragma unroll
                    for (int ni = 0; ni < 4; ++ni)
                        acc[mi][ni] = __builtin_amdgcn_mfma_f32_16x16x32_bf16(af[mi], bfr[ni], acc[mi][ni], 0, 0, 0);
            }
            __syncthreads();
        }
    }

#pragma unroll
    for (int ni = 0; ni < 4; ++ni) {
        const int nn = n0 + n_off + ni * 16 + fr;
        float scv = 1.f, bsv = 0.f;
        if (MODE != M_KPROJ) { scv = scale[nn]; bsv = bias[nn]; }
#pragma unroll
        for (int mi = 0; mi < 4; ++mi) {
            const int mb = p0 + m_off + mi * 16 + qd * 4;
#pragma unroll
            for (int r = 0; r < 4; ++r) {
                const int p = mb + r;
                const float v = acc[mi][ni][r];
                const int bb = p / 100, l = p - (p / 100) * 100;
                if (MODE == M_KPROJ) {
                    outf[(((size_t)(bb * 8 + (nn >> 5))) * 100 + l) * 32 + (nn & 31)] = v;
                } else {
                    const float y = v * scv + bsv;
                    const float a = y / (1.f + __expf(-y));
                    outf[(((size_t)(bb * 8 + (nn >> 5))) * 100 + l) * 32 + (nn & 31)] = a;
                }
            }
        }
    }
}

// ---- big-M conv body: 256x256 tile, 512 threads, 4-phase/K-tile counted-vmcnt pipeline ----
template <int MODE>
__device__ __forceinline__ void conv_body256(
    const bf16* __restrict__ in, const bf16* __restrict__ in2,
    const bf16* __restrict__ wr, const float* __restrict__ scale,
    const float* __restrict__ bias, const bf16* __restrict__ resid,
    bf16* __restrict__ outb, bf16* lA, bf16* lB,
    int mtile, int ntile)
{
    constexpr int CIN  = (MODE == M_C3) ? 512 : (MODE == M_CONV2 ? 768 : 256);
    constexpr int TAPS = (MODE == M_CONV2) ? 1 : 9;
    constexpr int K    = TAPS * CIN;
    constexpr int NT   = K / 64;
    constexpr int CPT  = CIN / 64;
    constexpr int L2C  = (CPT == 8) ? 3 : 2;
    constexpr int HP   = 42;

    const int t = threadIdx.x;
    const int p0 = mtile * 256;
    const int n0 = ntile * 256;

    const int row64 = t >> 3;
    const int chk = t & 7;
    const int src8 = (chk ^ (row64 & 7)) * 8;   // pre-swizzled global chunk
    const int dst8 = chk * 8;                   // linear LDS chunk

    const bf16* aBase[4];
    const bf16* aBase2[4];
#pragma unroll
    for (int si = 0; si < 4; ++si) {
        const int p = p0 + si * 64 + row64;
        const int b = p / 1600;
        const int s = p - b * 1600;
        const int oy = s / 40, ox = s - (s / 40) * 40;
        if (MODE == M_CONV2) {
            aBase[si]  = in  + ((size_t)(b * 22 + (oy >> 1) + 1) * 22 + (ox >> 1) + 1) * 512 + src8;
            aBase2[si] = in2 + ((size_t)(b * 1600 + oy * 40 + ox)) * 256 + src8;
        } else {
            aBase[si]  = in  + ((size_t)(b * HP + oy) * HP + ox) * CIN + src8;
            aBase2[si] = nullptr;
        }
    }
    const bf16* bBase[4];
#pragma unroll
    for (int si = 0; si < 4; ++si)
        bBase[si] = wr + (size_t)(n0 + si * 64 + row64) * K + src8;

    const int lane = t & 63;
    const int wv = t >> 6;
    const int m_off = (wv >> 2) * 128;      // 2 wave-rows
    const int n_off = (wv & 3) * 64;        // 4 wave-cols
    const int fr = lane & 15;
    const int qd = lane >> 4;
    const int xa = (fr & 7) << 4;

    f32x4 acc[8][4];
#pragma unroll
    for (int mi = 0; mi < 8; ++mi)
#pragma unroll
        for (int ni = 0; ni < 4; ++ni)
            acc[mi][ni] = (f32x4){0.f, 0.f, 0.f, 0.f};

#define LDA8(buf, rrow, kkk) \
    (*(const short8*)((const char*)lA + (buf) * 32768 + (rrow) * 128 + ((((kkk) * 64) + qd * 16) ^ xa)))
#define LDB8(buf, rrow, kkk) \
    (*(const short8*)((const char*)lB + (buf) * 32768 + (rrow) * 128 + ((((kkk) * 64) + qd * 16) ^ xa)))

    // ---- prologue: stage K-tile 0 fully into buffer 0 ----
#pragma unroll
    for (int si = 0; si < 4; ++si)
        gload_lds16(aBase[si], lA + (si * 64 + row64) * 64 + dst8);
#pragma unroll
    for (int si = 0; si < 4; ++si)
        gload_lds16(bBase[si], lB + (si * 64 + row64) * 64 + dst8);
    asm volatile("s_waitcnt vmcnt(0)" ::: "memory");
    __syncthreads();

#pragma clang loop unroll(disable)
    for (int kt = 0; kt < NT; ++kt) {
        const int cur = kt & 1;
        const int nxt = cur ^ 1;
        const int ktn = kt + 1;
        const bool pf = (ktn < NT);
        int offAn = 0, c0n = 0;
        if (pf) {
            if (MODE == M_CONV2) {
                c0n = ktn * 64;
            } else {
                const int tap = ktn >> L2C;
                const int ci = ktn & (CPT - 1);
                const int ky = tap / 3, kx = tap - ky * 3;
                offAn = (ky * HP + kx) * CIN + ci * 64;
            }
        }
        const int offBn = ktn * 64;

        auto stA = [&](int si) {
            const bf16* sa;
            if (MODE == M_CONV2) sa = (c0n < 512) ? (aBase[si] + c0n) : (aBase2[si] + (c0n - 512));
            else sa = aBase[si] + offAn;
            gload_lds16(sa, lA + nxt * 16384 + (si * 64 + row64) * 64 + dst8);
        };
        auto stB = [&](int si) {
            gload_lds16(bBase[si] + offBn, lB + nxt * 16384 + (si * 64 + row64) * 64 + dst8);
        };

        short8 af[4][2], bfr[4][2];

        // ===== P0: read A-h0(8) + B nf{0,1}(4); stage b0,b1,b2; MFMA acc[0..3][0..1] =====
#pragma unroll
        for (int m4 = 0; m4 < 4; ++m4) {
            af[m4][0] = LDA8(cur, m_off + m4 * 16 + fr, 0);
            af[m4][1] = LDA8(cur, m_off + m4 * 16 + fr, 1);
        }
#pragma unroll
        for (int n2 = 0; n2 < 2; ++n2) {
            bfr[n2][0] = LDB8(cur, n_off + n2 * 16 + fr, 0);
            bfr[n2][1] = LDB8(cur, n_off + n2 * 16 + fr, 1);
        }
        if (pf) { stB(0); stB(1); stB(2); }
        PH_BAR();
        WAIT_LGKM0();
        __builtin_amdgcn_s_setprio(1);
#pragma unroll
        for (int m4 = 0; m4 < 4; ++m4)
#pragma unroll
            for (int n2 = 0; n2 < 2; ++n2) {
                acc[m4][n2] = __builtin_amdgcn_mfma_f32_16x16x32_bf16(af[m4][0], bfr[n2][0], acc[m4][n2], 0, 0, 0);
                acc[m4][n2] = __builtin_amdgcn_mfma_f32_16x16x32_bf16(af[m4][1], bfr[n2][1], acc[m4][n2], 0, 0, 0);
            }
        __builtin_amdgcn_s_setprio(0);
        PH_BAR();

        // ===== P1: read B nf{2,3}(4); stage b3,a0,a2; MFMA acc[0..3][2..3]; VM6 =====
#pragma unroll
        for (int n2 = 2; n2 < 4; ++n2) {
            bfr[n2][0] = LDB8(cur, n_off + n2 * 16 + fr, 0);
            bfr[n2][1] = LDB8(cur, n_off + n2 * 16 + fr, 1);
        }
        if (pf) { stB(3); stA(0); stA(2); }
        PH_BAR();
        WAIT_LGKM0();
        __builtin_amdgcn_s_setprio(1);
#pragma unroll
        for (int m4 = 0; m4 < 4; ++m4)
#pragma unroll
            for (int n2 = 2; n2 < 4; ++n2) {
                acc[m4][n2] = __builtin_amdgcn_mfma_f32_16x16x32_bf16(af[m4][0], bfr[n2][0], acc[m4][n2], 0, 0, 0);
                acc[m4][n2] = __builtin_amdgcn_mfma_f32_16x16x32_bf16(af[m4][1], bfr[n2][1], acc[m4][n2], 0, 0, 0);
            }
        __builtin_amdgcn_s_setprio(0);
        // drain the cross-tile A-h1 loads (oldest 2) before P2 reads them
        if (pf) { WAIT_VM6(); } else { WAIT_VM0(); }
        PH_BAR();

        // ===== P2: read A-h1(8); MFMA acc[4..7][0..1] =====
#pragma unroll
        for (int m4 = 0; m4 < 4; ++m4) {
            af[m4][0] = LDA8(cur, m_off + (4 + m4) * 16 + fr, 0);
            af[m4][1] = LDA8(cur, m_off + (4 + m4) * 16 + fr, 1);
        }
        PH_BAR();
        WAIT_LGKM0();
        __builtin_amdgcn_s_setprio(1);
#pragma unroll
        for (int m4 = 0; m4 < 4; ++m4)
#pragma unroll
            for (int n2 = 0; n2 < 2; ++n2) {
                acc[4 + m4][n2] = __builtin_amdgcn_mfma_f32_16x16x32_bf16(af[m4][0], bfr[n2][0], acc[4 + m4][n2], 0, 0, 0);
                acc[4 + m4][n2] = __builtin_amdgcn_mfma_f32_16x16x32_bf16(af[m4][1], bfr[n2][1], acc[4 + m4][n2], 0, 0, 0);
            }
        __builtin_amdgcn_s_setprio(0);
        PH_BAR();

        // ===== P3: stage a1,a3; MFMA acc[4..7][2..3]; VM2 =====
        if (pf) { stA(1); stA(3); }
        __builtin_amdgcn_s_setprio(1);
#pragma unroll
        for (int m4 = 0; m4 < 4; ++m4)
#pragma unroll
            for (int n2 = 2; n2 < 4; ++n2) {
                acc[4 + m4][n2] = __builtin_amdgcn_mfma_f32_16x16x32_bf16(af[m4][0], bfr[n2][0], acc[4 + m4][n2], 0, 0, 0);
                acc[4 + m4][n2] = __builtin_amdgcn_mfma_f32_16x16x32_bf16(af[m4][1], bfr[n2][1], acc[4 + m4][n2], 0, 0, 0);
            }
        __builtin_amdgcn_s_setprio(0);
        // counted: leave only the 2 newest (a1,a3 of nxt) in flight across the boundary
        if (pf) { WAIT_VM2(); }
        PH_BAR();
    }
#undef LDA8
#undef LDB8

    // ---- epilogue ----
#pragma unroll
    for (int ni = 0; ni < 4; ++ni) {
        const int nn = n0 + n_off + ni * 16 + fr;
        const float scv = scale[nn];
        const float bsv = bias[nn];
#pragma unroll
        for (int mi = 0; mi < 8; ++mi) {
            const int mb = p0 + m_off + mi * 16 + qd * 4;
#pragma unroll
            for (int r = 0; r < 4; ++r) {
                const int p = mb + r;
                const float y = acc[mi][ni][r] * scv + bsv;
                const float a = y / (1.f + __expf(-y));
                if (MODE == M_SA1) {
                    const int bb = p / 1600; const int s = p - bb * 1600;
                    const int oy = s / 40, ox = s - (s / 40) * 40;
                    outb[(((size_t)(bb * 42 + oy + 1)) * 42 + ox + 1) * 256 + nn] = f2b(a);
                } else if (MODE == M_SA2) {
                    const int bb = p / 1600; const int s = p - bb * 1600;
                    const int oy = s / 40, ox = s - (s / 40) * 40;
                    const size_t roff = (((size_t)(bb * 42 + oy + 1)) * 42 + ox + 1) * 256 + nn;
                    outb[(size_t)p * 256 + nn] = f2b(a + b2f(resid[roff]));
                } else if (MODE == M_C3) {
                    const int bb = p / 1600; const int s = p - bb * 1600;
                    const int oy = s / 40, ox = s - (s / 40) * 40;
                    const size_t roff = (((size_t)(bb * 42 + oy + 1)) * 42 + ox + 1) * 512 + nn;
                    outb[(size_t)p * 512 + nn] = f2b(a + b2f(resid[roff]));
                } else { // M_CONV2
                    outb[(size_t)p * 512 + nn] = f2b(a);
                }
            }
        }
    }
}

// single-mode wrapper (SA2: 200 blocks, CONV2: 400 blocks)
template <int MODE>
__global__ __launch_bounds__(512, 2)
void conv_mfma256(const bf16* __restrict__ in, const bf16* __restrict__ in2,
                  const bf16* __restrict__ wr,
                  const float* __restrict__ scale, const float* __restrict__ bias,
                  const bf16* __restrict__ resid,
                  bf16* __restrict__ outb)
{
    __shared__ bf16 Al[2][256][64];
    __shared__ bf16 Bl[2][256][64];
    int mtile, ntile;
    if (MODE == M_CONV2 || MODE == M_C3) { mtile = blockIdx.x >> 1; ntile = blockIdx.x & 1; }
    else { mtile = blockIdx.x; ntile = 0; }
    conv_body256<MODE>(in, in2, wr, scale, bias, resid, outb,
                       &Al[0][0][0], &Bl[0][0][0], mtile, ntile);
}

// merged C3 + SA1 launch: C3 (long blocks) first for LPT dispatch, SA1 backfills
__global__ __launch_bounds__(512, 2)
void conv_c3_sa1(const bf16* __restrict__ attn, const bf16* __restrict__ wc3,
                 const float* __restrict__ c3_s, const float* __restrict__ c3_b,
                 bf16* __restrict__ x2o,
                 const bf16* __restrict__ xca, const bf16* __restrict__ wsa1,
                 const float* __restrict__ sa1_s, const float* __restrict__ sa1_b,
                 bf16* __restrict__ tbuf)
{
    __shared__ bf16 Al[2][256][64];
    __shared__ bf16 Bl[2][256][64];
    const int bx = blockIdx.x;
    if (bx < 400) {
        conv_body256<M_C3>(attn, nullptr, wc3, c3_s, c3_b, attn, x2o,
                           &Al[0][0][0], &Bl[0][0][0], bx >> 1, bx & 1);
    } else {
        conv_body256<M_SA1>(xca, nullptr, wsa1, sa1_s, sa1_b, nullptr, tbuf,
                            &Al[0][0][0], &Bl[0][0][0], bx - 400, 0);
    }
}

extern "C" void kernel_launch(void* const* d_in, const int* in_sizes, int n_in,
                              void* d_out, int out_size, void* d_ws, size_t ws_size,
                              hipStream_t stream)
{
    const float* x1      = (const float*)d_in[0];
    const float* x2      = (const float*)d_in[1];
    const float* q_w     = (const float*)d_in[2];
    const float* q_s     = (const float*)d_in[3];
    const float* q_b     = (const float*)d_in[4];
    const float* key_w   = (const float*)d_in[5];
    const float* ca_w1   = (const float*)d_in[6];
    const float* ca_b1   = (const float*)d_in[7];
    const float* ca_w2   = (const float*)d_in[8];
    const float* ca_b2   = (const float*)d_in[9];
    const float* sa1_w   = (const float*)d_in[10];
    const float* sa1_s   = (const float*)d_in[11];
    const float* sa1_b   = (const float*)d_in[12];
    const float* sa2_w   = (const float*)d_in[13];
    const float* sa2_s   = (const float*)d_in[14];
    const float* sa2_b   = (const float*)d_in[15];
    const float* conv2_w = (const float*)d_in[16];
    const float* conv2_s = (const float*)d_in[17];
    const float* conv2_b = (const float*)d_in[18];
    const float* c3_w    = (const float*)d_in[19];
    const float* c3_s    = (const float*)d_in[20];
    const float* c3_b    = (const float*)d_in[21];

    char* ws = (char*)d_ws;
    // workspace layout (bytes) — padded NHWC buffers, aggressive aliasing; peak 213,254,144
    const size_t o_x1n  = 0;                 // 32*22*22*512 bf16 : 15,859,712 (halo)
    const size_t o_x2n  = 15859712;          // 32*1600*512 bf16  : 52,428,800 (x2o alias after attn)
    const size_t o_attn = 68288512;          // 32*42*42*512 bf16 : 57,802,752 (halo; x1o alias after C3)
    const size_t o_xca  = 126091264;         // 32*42*42*256 bf16 : 28,901,376 (halo; live through SA2)
    const size_t o_tbuf = 154992640;         // 32*42*42*256 bf16 : 28,901,376 (halo; k/q/wkey alias before SA1)
    const size_t o_a2   = 183894016;         // 32*1600*256 bf16  : 26,214,400 (kp/wq/wc3 alias before SA2)
    const size_t o_ws1  = 210108416;         // 256*2304 bf16 : 1,179,648
    const size_t o_ws2  = 211288064;         // 256*2304 bf16 : 1,179,648
    const size_t o_wc2  = 212467712;         // 512*768  bf16 :   786,432
    // aliases
    const size_t o_k    = o_tbuf;            // 3,276,800 f32
    const size_t o_q    = o_tbuf + 3276800;  // 3,276,800 f32
    const size_t o_wkey = o_tbuf + 6553600;  //   262,144 bf16
    const size_t o_kp   = o_a2;              // 3,276,800 bf16
    const size_t o_wq   = o_a2 + 3276800;    // 2,359,296 bf16
    const size_t o_wc3  = o_a2 + 5636096;    // 4,718,592 bf16 (dead before SA2 writes a2)

    bf16*  x1n    = (bf16*)(ws + o_x1n);
    bf16*  x2n    = (bf16*)(ws + o_x2n);
    float* k_attn = (float*)(ws + o_k);
    float* q_attn = (float*)(ws + o_q);
    bf16*  attn   = (bf16*)(ws + o_attn);
    bf16*  xca    = (bf16*)(ws + o_xca);
    bf16*  tbuf   = (bf16*)(ws + o_tbuf);
    bf16*  a2     = (bf16*)(ws + o_a2);
    bf16*  wq     = (bf16*)(ws + o_wq);
    bf16*  wc3    = (bf16*)(ws + o_wc3);
    bf16*  wsa1   = (bf16*)(ws + o_ws1);
    bf16*  wsa2   = (bf16*)(ws + o_ws2);
    bf16*  kp     = (bf16*)(ws + o_kp);
    bf16*  wkey   = (bf16*)(ws + o_wkey);
    bf16*  wc2    = (bf16*)(ws + o_wc2);
    bf16*  x2o    = (bf16*)(ws + o_x2n);     // alias: x2n dead after attn_kernel
    bf16*  x1o    = (bf16*)(ws + o_attn);    // alias: attn dead after C3

    const dim3 blk(256);
    const dim3 blk512(512);

    halo_zero<<<dim3(32, 22), blk, 0, stream>>>(x1n, 20, 512);
    halo_zero<<<dim3(32, 42), blk, 0, stream>>>(xca, 40, 256);
    halo_zero<<<dim3(32, 42), blk, 0, stream>>>(attn, 40, 512);

    nchw_to_nhwc<<<dim3(32, 7, 8), blk, 0, stream>>>(x1, x1n, 512, 20, 20, 1);
    nchw_to_nhwc<<<dim3(32, 25, 8), blk, 0, stream>>>(x2, x2n, 512, 40, 40, 0);
    reorder_w<<<4608, blk, 0, stream>>>(q_w,  wq,   512, 256 * 512 * 9);
    reorder_w<<<9216, blk, 0, stream>>>(c3_w, wc3,  512, 512 * 512 * 9);
    reorder_w<<<2304, blk, 0, stream>>>(sa1_w, wsa1, 256, 256 * 256 * 9);
    reorder_w<<<2304, blk, 0, stream>>>(sa2_w, wsa2, 256, 256 * 256 * 9);
    f32_to_bf16<<<512, blk, 0, stream>>>(key_w, wkey, 256 * 512);
    f32_to_bf16<<<1536, blk, 0, stream>>>(conv2_w, wc2, 512 * 768);
    pool_kp<<<3200, blk, 0, stream>>>(x2n, kp);

    conv_mfma<M_KPROJ><<<dim3(25, 2), blk, 0, stream>>>(kp, wkey, nullptr, nullptr, k_attn);
    conv_mfma<M_QCONV><<<dim3(25, 2), blk, 0, stream>>>(x1n, wq, q_s, q_b, q_attn);

    attn_kernel<<<256, blk, 0, stream>>>(q_attn, k_attn, x2n, attn);

    // k/q/wkey dead now; zero tbuf halo before SA1 writes into it
    halo_zero<<<dim3(32, 42), blk, 0, stream>>>(tbuf, 40, 256);

    ca_mlp<<<12800, blk, 0, stream>>>(x1n, ca_w1, ca_b1, ca_w2, ca_b2, xca);

    // merged: C3 (blocks 0-399) + SA1 (blocks 400-599) — independent, LPT-balanced
    conv_c3_sa1<<<600, blk512, 0, stream>>>(attn, wc3, c3_s, c3_b, x2o,
                                            xca, wsa1, sa1_s, sa1_b, tbuf);

    conv_mfma256<M_SA2><<<200, blk512, 0, stream>>>(tbuf, nullptr, wsa2,
        sa2_s, sa2_b, xca, a2);
    conv_mfma256<M_CONV2><<<400, blk512, 0, stream>>>(x1n, a2, wc2,
        conv2_s, conv2_b, nullptr, x1o);

    pack_out<<<dim3(32, 25, 16), blk, 0, stream>>>(x1o, x2o, (float*)d_out);

    (void)in_sizes; (void)n_in; (void)out_size; (void)ws_size;
}

// Round 6
// 1392.655 us; speedup vs baseline: 1.0577x; 1.0212x over previous
//
#include <hip/hip_runtime.h>
#include <hip/hip_bf16.h>

using bf16 = __hip_bfloat16;
using bf16x2 = __hip_bfloat162;
typedef __attribute__((ext_vector_type(8))) short short8;
typedef __attribute__((ext_vector_type(4))) float f32x4;

__device__ __forceinline__ float b2f(bf16 v) { return __bfloat162float(v); }
__device__ __forceinline__ bf16 f2b(float v) { return __float2bfloat16(v); }

// async global->LDS, 16B per lane; dest must be wave-uniform base + lane*16
__device__ __forceinline__ void gload_lds16(const bf16* g, bf16* l)
{
    __builtin_amdgcn_global_load_lds(
        (const __attribute__((address_space(1))) void*)g,
        (__attribute__((address_space(3))) void*)l,
        16, 0, 0);
}

#define PH_BAR() do { __builtin_amdgcn_sched_barrier(0); __builtin_amdgcn_s_barrier(); __builtin_amdgcn_sched_barrier(0); } while (0)
#define WAIT_VM0() do { asm volatile("s_waitcnt vmcnt(0)" ::: "memory"); __builtin_amdgcn_sched_barrier(0); } while (0)
#define WAIT_VM2() do { asm volatile("s_waitcnt vmcnt(2)" ::: "memory"); __builtin_amdgcn_sched_barrier(0); } while (0)
#define WAIT_VM6() do { asm volatile("s_waitcnt vmcnt(6)" ::: "memory"); __builtin_amdgcn_sched_barrier(0); } while (0)

// ---------------- NCHW f32 -> NHWC bf16 transpose (optionally halo-padded out) ----------------
__global__ __launch_bounds__(256) void nchw_to_nhwc(const float* __restrict__ in,
                                                    bf16* __restrict__ out,
                                                    int C, int H, int W, int pad)
{
    __shared__ bf16 tile[64][68];
    const int S = H * W;
    const int HP = H + 2 * pad, WP = W + 2 * pad;
    const int b = blockIdx.x, s0 = blockIdx.y * 64, c0 = blockIdx.z * 64;
    const int t = threadIdx.x;
    const int a = t & 63, q = t >> 6;
#pragma unroll
    for (int i = 0; i < 16; ++i) {
        int cl = q + i * 4;
        int s = s0 + a;
        tile[cl][a] = (s < S) ? f2b(in[((size_t)b * C + c0 + cl) * S + s]) : f2b(0.f);
    }
    __syncthreads();
#pragma unroll
    for (int i = 0; i < 16; ++i) {
        int sl = q + i * 4;
        int s = s0 + sl;
        if (s < S) {
            int y = s / W, x = s - (s / W) * W;
            out[(((size_t)b * HP + y + pad) * WP + x + pad) * C + c0 + a] = tile[a][sl];
        }
    }
}

// ---------------- zero the 1-px halo of a padded NHWC buffer ----------------
__global__ __launch_bounds__(256) void halo_zero(bf16* __restrict__ buf, int W, int C)
{
    const int b = blockIdx.x, y = blockIdx.y;
    const int P = W + 2;
    const bf16 z = f2b(0.f);
    bf16* row = buf + ((size_t)b * P + y) * P * C;
    if (y == 0 || y == P - 1) {
        for (int i = threadIdx.x; i < P * C; i += 256) row[i] = z;
    } else {
        for (int i = threadIdx.x; i < 2 * C; i += 256) {
            const int x = (i < C) ? 0 : P - 1;
            const int c = (i < C) ? i : i - C;
            row[(size_t)x * C + c] = z;
        }
    }
}

// ---------------- pack NHWC bf16 halves -> NCHW f32 concat output ----------------
__global__ __launch_bounds__(256) void pack_out(const bf16* __restrict__ x1o,
                                                const bf16* __restrict__ x2o,
                                                float* __restrict__ out)
{
    __shared__ bf16 tile[64][68];
    const int b = blockIdx.x, s0 = blockIdx.y * 64, ch0 = blockIdx.z * 64;
    const bf16* src = (ch0 < 512) ? x1o : x2o;
    const int c0 = ch0 & 511;
    const int t = threadIdx.x;
    const int a = t & 63, q = t >> 6;
#pragma unroll
    for (int i = 0; i < 16; ++i) {
        int sl = q + i * 4;
        tile[sl][a] = src[((size_t)b * 1600 + s0 + sl) * 512 + c0 + a];
    }
    __syncthreads();
#pragma unroll
    for (int i = 0; i < 16; ++i) {
        int cl = q + i * 4;
        out[((size_t)b * 1024 + ch0 + cl) * 1600 + s0 + a] = b2f(tile[a][cl]);
    }
}

// ------- weight reorder+convert: w[o][c][ky][kx] f32 -> wr[o][(ky*3+kx)*C + c] bf16 -------
__global__ __launch_bounds__(256) void reorder_w(const float* __restrict__ w,
                                                 bf16* __restrict__ wr,
                                                 int C, int total)
{
    int i = blockIdx.x * 256 + threadIdx.x;
    if (i >= total) return;
    int nineC = 9 * C;
    int o = i / nineC;
    int r = i - o * nineC;
    int tap = r / C;
    int c = r - tap * C;
    wr[i] = f2b(w[((size_t)o * C + c) * 9 + tap]);
}

// ---------------- plain f32 -> bf16 convert ----------------
__global__ __launch_bounds__(256) void f32_to_bf16(const float* __restrict__ in,
                                                   bf16* __restrict__ out, int n)
{
    int i = blockIdx.x * 256 + threadIdx.x;
    if (i < n) out[i] = f2b(in[i]);
}

// ---------------- patch mean pool: x2 NHWC -> kp[b*100][512] bf16 ----------------
__global__ __launch_bounds__(256) void pool_kp(const bf16* __restrict__ x2n,
                                               bf16* __restrict__ kp)
{
    const int p = blockIdx.x;            // b*100 + l
    const int b = p / 100, l = p - (p / 100) * 100;
    const int ph = l / 10, pw = l - (l / 10) * 10;
    const int t = threadIdx.x;           // 256 threads, 2 channels each
    const bf16x2* base = (const bf16x2*)(x2n + (((size_t)(b * 40 + ph * 4) * 40) + pw * 4) * 512) + t;
    float sx = 0.f, sy = 0.f;
#pragma unroll
    for (int py = 0; py < 4; ++py)
#pragma unroll
        for (int px = 0; px < 4; ++px) {
            float2 v = __bfloat1622float2(base[(py * 40 + px) * 256]);
            sx += v.x; sy += v.y;
        }
    ((bf16x2*)(kp + (size_t)p * 512))[t] = __float22bfloat162_rn(make_float2(sx * 0.0625f, sy * 0.0625f));
}

// ---------------- channel-attention MLP at 20x20 source resolution ----------------
__global__ __launch_bounds__(256) void ca_mlp(const bf16* __restrict__ x1n,
                                              const float* __restrict__ w1, const float* __restrict__ b1,
                                              const float* __restrict__ w2, const float* __restrict__ b2,
                                              bf16* __restrict__ xca)
{
    __shared__ float a1v[256];
    __shared__ float part[4][64];
    __shared__ float hid[64];
    const int blk = blockIdx.x;
    const int b = blk / 400;
    const int rem = blk - b * 400;
    const int y = rem / 20, x = rem - (rem / 20) * 20;
    const int t = threadIdx.x;
    const bf16* src = x1n + ((size_t)(b * 22 + y + 1) * 22 + x + 1) * 512 + 256;
    a1v[t] = b2f(src[t]);
    __syncthreads();
    {
        const int h = t & 63, seg = t >> 6;
        float acc = 0.f;
        const float* wp = w1 + (size_t)h * 256 + seg * 64;
        const float* ap = a1v + seg * 64;
#pragma unroll 8
        for (int c = 0; c < 64; ++c) acc += wp[c] * ap[c];
        part[seg][h] = acc;
    }
    __syncthreads();
    if (t < 64)
        hid[t] = fmaxf(part[0][t] + part[1][t] + part[2][t] + part[3][t] + b1[t], 0.f);
    __syncthreads();
    float acc2 = b2[t];
    const float* w2p = w2 + (size_t)t * 64;
#pragma unroll 8
    for (int h = 0; h < 64; ++h) acc2 += w2p[h] * hid[h];
    const float g = 1.f / (1.f + __expf(-acc2));
    const bf16 o = f2b(a1v[t] * g);
    const size_t obase = ((size_t)(b * 42 + 2 * y + 1) * 42 + 2 * x + 1) * 256 + t;
    xca[obase] = o;
    xca[obase + 256] = o;
    xca[obase + 42 * 256] = o;
    xca[obase + 42 * 256 + 256] = o;
}

// ---------------- attention: one block per (batch,head) ----------------
__global__ __launch_bounds__(256, 1)
void attn_kernel(const float* __restrict__ q, const float* __restrict__ k,
                 const bf16* __restrict__ x2n, bf16* __restrict__ attn)
{
    __shared__ float sc[100][100];
    __shared__ bf16 wT[100][104];   // wT[l][ql]
    const int t = threadIdx.x;
    const int n = blockIdx.x;
    const int b = n >> 3, hd = n & 7;
    const float* qn = q + (size_t)n * 3200;
    const float* kn = k + (size_t)n * 3200;
    for (int e = t; e < 10000; e += 256) {
        const int i = e / 100;
        const int j = e - i * 100;
        const float4* qa = (const float4*)(qn + i * 32);
        const float4* ka = (const float4*)(kn + j * 32);
        float d = 0.f;
#pragma unroll
        for (int u = 0; u < 8; ++u) {
            float4 xv = qa[u], yv = ka[u];
            d += xv.x * yv.x + xv.y * yv.y + xv.z * yv.z + xv.w * yv.w;
        }
        sc[i][j] = d * 0.17677669529663687f;   // 1/sqrt(32)
    }
    __syncthreads();
    if (t < 100) {
        float mx = -1e30f;
        for (int j = 0; j < 100; ++j) mx = fmaxf(mx, sc[t][j]);
        float s = 0.f;
        for (int j = 0; j < 100; ++j) s += __expf(sc[t][j] - mx);
        const float inv = 1.f / s;
        for (int j = 0; j < 100; ++j) wT[j][t] = f2b(__expf(sc[t][j] - mx) * inv);
    }
    __syncthreads();
    const int ch0 = (t & 15) * 4;
    const int pix = t >> 4;
    const int py = pix >> 2, px = pix & 3;
    const bf16* vbase = x2n + (((size_t)(b * 40 + py) * 40) + px) * 512 + hd * 64 + ch0;
    for (int ql0 = 0; ql0 < 100; ql0 += 20) {
        float2 a0[20], a1[20];
#pragma unroll
        for (int i = 0; i < 20; ++i) { a0[i] = make_float2(0.f, 0.f); a1[i] = make_float2(0.f, 0.f); }
        for (int l = 0; l < 100; ++l) {
            const int ph = l / 10, pw = l - (l / 10) * 10;
            const bf16* vp = vbase + ((size_t)(ph * 160 + pw * 4)) * 512;
            const float2 v01 = __bfloat1622float2(*(const bf16x2*)vp);
            const float2 v23 = __bfloat1622float2(*(const bf16x2*)(vp + 2));
            const bf16x2* wp = (const bf16x2*)&wT[l][ql0];
#pragma unroll
            for (int ii = 0; ii < 10; ++ii) {
                const float2 w2 = __bfloat1622float2(wp[ii]);
                a0[ii * 2 + 0].x += w2.x * v01.x; a0[ii * 2 + 0].y += w2.x * v01.y;
                a1[ii * 2 + 0].x += w2.x * v23.x; a1[ii * 2 + 0].y += w2.x * v23.y;
                a0[ii * 2 + 1].x += w2.y * v01.x; a0[ii * 2 + 1].y += w2.y * v01.y;
                a1[ii * 2 + 1].x += w2.y * v23.x; a1[ii * 2 + 1].y += w2.y * v23.y;
            }
        }
#pragma unroll
        for (int i = 0; i < 20; ++i) {
            const int ql = ql0 + i;
            const int ph = ql / 10, pw = ql - (ql / 10) * 10;
            bf16* op = attn + (((size_t)(b * 42 + ph * 4 + py + 1) * 42) + pw * 4 + px + 1) * 512 + hd * 64 + ch0;
            *(bf16x2*)op = __float22bfloat162_rn(a0[i]);
            *(bf16x2*)(op + 2) = __float22bfloat162_rn(a1[i]);
        }
    }
}

enum ConvMode { M_QCONV = 0, M_SA1 = 1, M_SA2 = 2, M_C3 = 3, M_CONV2 = 4, M_KPROJ = 5 };

// ---------------- small-M implicit-GEMM MFMA conv (128x128 tile) for QCONV/KPROJ ----------------
template <int MODE>
__global__ __launch_bounds__(256, 2)
void conv_mfma(const bf16* __restrict__ in, const bf16* __restrict__ wr,
               const float* __restrict__ scale, const float* __restrict__ bias,
               float* __restrict__ outf)
{
    constexpr int CIN  = 512;
    constexpr int TAPS = (MODE == M_KPROJ) ? 1 : 9;
    constexpr int STR  = 2;
    constexpr int HP   = 22;
    constexpr int WOUT = 10;
    constexpr int K    = TAPS * CIN;
    constexpr int KD   = (TAPS == 9) ? 3 : 1;

    __shared__ bf16 Al[128][64];
    __shared__ bf16 Bl[128][64];

    const int t = threadIdx.x;
    const int p0 = blockIdx.x * 128;
    const int n0 = blockIdx.y * 128;

    int s_row[4], s_dst8[4], s_src8[4], s_b[4], s_oy[4], s_ox[4];
    const bf16* bB[4];
#pragma unroll
    for (int i = 0; i < 4; ++i) {
        const int task = t + i * 256;
        const int row = task >> 3, chk = task & 7;
        s_row[i] = row;
        s_dst8[i] = chk * 8;
        s_src8[i] = (chk ^ (row & 7)) * 8;
        const int p = p0 + row;
        const int bb = p / 100;
        const int s = p - bb * 100;
        s_b[i] = bb;
        s_oy[i] = s / WOUT;
        s_ox[i] = s - s_oy[i] * WOUT;
        bB[i] = wr + (size_t)(n0 + row) * K + s_src8[i];
    }

    const bf16* aP1[4];
    if (MODE == M_KPROJ) {
#pragma unroll
        for (int i = 0; i < 4; ++i)
            aP1[i] = in + (size_t)(p0 + s_row[i]) * 512 + s_src8[i];
    }

    const int lane = t & 63;
    const int wv = t >> 6;
    const int m_off = (wv >> 1) * 64;
    const int n_off = (wv & 1) * 64;
    const int fr = lane & 15;
    const int qd = lane >> 4;
    const int xa = (fr & 7) << 4;

    f32x4 acc[4][4];
#pragma unroll
    for (int mi = 0; mi < 4; ++mi)
#pragma unroll
        for (int ni = 0; ni < 4; ++ni)
            acc[mi][ni] = (f32x4){0.f, 0.f, 0.f, 0.f};

    for (int ky = 0; ky < KD; ++ky)
    for (int kx = 0; kx < KD; ++kx) {
        const bf16* aT[4];
        if (TAPS == 9) {
#pragma unroll
            for (int i = 0; i < 4; ++i)
                aT[i] = in + ((size_t)((s_b[i] * HP + s_oy[i] * STR + ky) * HP) + s_ox[i] * STR + kx) * CIN + s_src8[i];
        }
        const int kk0 = (ky * KD + kx) * CIN;
        for (int c0 = 0; c0 < CIN; c0 += 64) {
#pragma unroll
            for (int i = 0; i < 4; ++i) {
                const bf16* sa = (MODE == M_KPROJ) ? (aP1[i] + c0) : (aT[i] + c0);
                gload_lds16(sa, &Al[s_row[i]][s_dst8[i]]);
            }
#pragma unroll
            for (int i = 0; i < 4; ++i)
                gload_lds16(bB[i] + (kk0 + c0), &Bl[s_row[i]][s_dst8[i]]);
            __syncthreads();
#pragma unroll
            for (int ks = 0; ks < 2; ++ks) {
                short8 af[4], bfr[4];
                const int coff = (ks * 64 + qd * 16) ^ xa;
#pragma unroll
                for (int mi = 0; mi < 4; ++mi)
                    af[mi] = *(const short8*)((const char*)&Al[m_off + mi * 16 + fr][0] + coff);
#pragma unroll
                for (int ni = 0; ni < 4; ++ni)
                    bfr[ni] = *(const short8*)((const char*)&Bl[n_off + ni * 16 + fr][0] + coff);
#pragma unroll
                for (int mi = 0; mi < 4; ++mi)
#pragma unroll
                    for (int ni = 0; ni < 4; ++ni)
                        acc[mi][ni] = __builtin_amdgcn_mfma_f32_16x16x32_bf16(af[mi], bfr[ni], acc[mi][ni], 0, 0, 0);
            }
            __syncthreads();
        }
    }

#pragma unroll
    for (int ni = 0; ni < 4; ++ni) {
        const int nn = n0 + n_off + ni * 16 + fr;
        float scv = 1.f, bsv = 0.f;
        if (MODE != M_KPROJ) { scv = scale[nn]; bsv = bias[nn]; }
#pragma unroll
        for (int mi = 0; mi < 4; ++mi) {
            const int mb = p0 + m_off + mi * 16 + qd * 4;
#pragma unroll
            for (int r = 0; r < 4; ++r) {
                const int p = mb + r;
                const float v = acc[mi][ni][r];
                const int bb = p / 100, l = p - (p / 100) * 100;
                if (MODE == M_KPROJ) {
                    outf[(((size_t)(bb * 8 + (nn >> 5))) * 100 + l) * 32 + (nn & 31)] = v;
                } else {
                    const float y = v * scv + bsv;
                    const float a = y / (1.f + __expf(-y));
                    outf[(((size_t)(bb * 8 + (nn >> 5))) * 100 + l) * 32 + (nn & 31)] = a;
                }
            }
        }
    }
}

// ---- big-M conv body: 256x256 tile, 512 threads, 2-region/K-tile counted-vmcnt pipeline ----
// Regions are compiler-scheduled (no lgkm pins) so the LDS pipe overlaps the matrix pipe;
// only tile-boundary hazards are fenced (counted vmcnt + raw barrier + sched_barrier).
template <int MODE>
__device__ __forceinline__ void conv_body256(
    const bf16* __restrict__ in, const bf16* __restrict__ in2,
    const bf16* __restrict__ wr, const float* __restrict__ scale,
    const float* __restrict__ bias, const bf16* __restrict__ resid,
    bf16* __restrict__ outb, bf16* lA, bf16* lB,
    int mtile, int ntile)
{
    constexpr int CIN  = (MODE == M_C3) ? 512 : (MODE == M_CONV2 ? 768 : 256);
    constexpr int TAPS = (MODE == M_CONV2) ? 1 : 9;
    constexpr int K    = TAPS * CIN;
    constexpr int NT   = K / 64;
    constexpr int CPT  = CIN / 64;
    constexpr int L2C  = (CPT == 8) ? 3 : 2;
    constexpr int HP   = 42;

    const int t = threadIdx.x;
    const int p0 = mtile * 256;
    const int n0 = ntile * 256;

    const int row64 = t >> 3;
    const int chk = t & 7;
    const int src8 = (chk ^ (row64 & 7)) * 8;   // pre-swizzled global chunk
    const int dst8 = chk * 8;                   // linear LDS chunk

    const bf16* aBase[4];
    const bf16* aBase2[4];
#pragma unroll
    for (int si = 0; si < 4; ++si) {
        const int p = p0 + si * 64 + row64;
        const int b = p / 1600;
        const int s = p - b * 1600;
        const int oy = s / 40, ox = s - (s / 40) * 40;
        if (MODE == M_CONV2) {
            aBase[si]  = in  + ((size_t)(b * 22 + (oy >> 1) + 1) * 22 + (ox >> 1) + 1) * 512 + src8;
            aBase2[si] = in2 + ((size_t)(b * 1600 + oy * 40 + ox)) * 256 + src8;
        } else {
            aBase[si]  = in  + ((size_t)(b * HP + oy) * HP + ox) * CIN + src8;
            aBase2[si] = nullptr;
        }
    }
    const bf16* bBase[4];
#pragma unroll
    for (int si = 0; si < 4; ++si)
        bBase[si] = wr + (size_t)(n0 + si * 64 + row64) * K + src8;

    const int lane = t & 63;
    const int wv = t >> 6;
    const int m_off = (wv >> 2) * 128;      // 2 wave-rows
    const int n_off = (wv & 3) * 64;        // 4 wave-cols
    const int fr = lane & 15;
    const int qd = lane >> 4;
    const int xa = (fr & 7) << 4;

    f32x4 acc[8][4];
#pragma unroll
    for (int mi = 0; mi < 8; ++mi)
#pragma unroll
        for (int ni = 0; ni < 4; ++ni)
            acc[mi][ni] = (f32x4){0.f, 0.f, 0.f, 0.f};

#define LDA8(buf, rrow, kkk) \
    (*(const short8*)((const char*)lA + (buf) * 32768 + (rrow) * 128 + ((((kkk) * 64) + qd * 16) ^ xa)))
#define LDB8(buf, rrow, kkk) \
    (*(const short8*)((const char*)lB + (buf) * 32768 + (rrow) * 128 + ((((kkk) * 64) + qd * 16) ^ xa)))

    // ---- prologue: stage K-tile 0 fully into buffer 0 ----
#pragma unroll
    for (int si = 0; si < 4; ++si)
        gload_lds16(aBase[si], lA + (si * 64 + row64) * 64 + dst8);
#pragma unroll
    for (int si = 0; si < 4; ++si)
        gload_lds16(bBase[si], lB + (si * 64 + row64) * 64 + dst8);
    asm volatile("s_waitcnt vmcnt(0)" ::: "memory");
    __syncthreads();

#pragma clang loop unroll(disable)
    for (int kt = 0; kt < NT; ++kt) {
        const int cur = kt & 1;
        const int nxt = cur ^ 1;
        const int ktn = kt + 1;
        const bool pf = (ktn < NT);
        int offAn = 0, c0n = 0;
        if (pf) {
            if (MODE == M_CONV2) {
                c0n = ktn * 64;
            } else {
                const int tap = ktn >> L2C;
                const int ci = ktn & (CPT - 1);
                const int ky = tap / 3, kx = tap - ky * 3;
                offAn = (ky * HP + kx) * CIN + ci * 64;
            }
        }
        const int offBn = ktn * 64;

        auto stA = [&](int si) {
            const bf16* sa;
            if (MODE == M_CONV2) sa = (c0n < 512) ? (aBase[si] + c0n) : (aBase2[si] + (c0n - 512));
            else sa = aBase[si] + offAn;
            gload_lds16(sa, lA + nxt * 16384 + (si * 64 + row64) * 64 + dst8);
        };
        auto stB = [&](int si) {
            gload_lds16(bBase[si] + offBn, lB + nxt * 16384 + (si * 64 + row64) * 64 + dst8);
        };

        short8 af[4][2], bfr[4][2];

        // ===== Region 1: reads A-h0(8)+B(8); stage Sx={b0..b3,a0,a2}; MFMA acc[0..3][*] =====
        // no lgkm pins — compiler interleaves MFMA with fine-grained lgkmcnt
#pragma unroll
        for (int m4 = 0; m4 < 4; ++m4) {
            af[m4][0] = LDA8(cur, m_off + m4 * 16 + fr, 0);
            af[m4][1] = LDA8(cur, m_off + m4 * 16 + fr, 1);
        }
#pragma unroll
        for (int n4 = 0; n4 < 4; ++n4) {
            bfr[n4][0] = LDB8(cur, n_off + n4 * 16 + fr, 0);
            bfr[n4][1] = LDB8(cur, n_off + n4 * 16 + fr, 1);
        }
        if (pf) { stB(0); stB(1); stB(2); stB(3); stA(0); stA(2); }
        __builtin_amdgcn_s_setprio(1);
#pragma unroll
        for (int m4 = 0; m4 < 4; ++m4)
#pragma unroll
            for (int n4 = 0; n4 < 4; ++n4) {
                acc[m4][n4] = __builtin_amdgcn_mfma_f32_16x16x32_bf16(af[m4][0], bfr[n4][0], acc[m4][n4], 0, 0, 0);
                acc[m4][n4] = __builtin_amdgcn_mfma_f32_16x16x32_bf16(af[m4][1], bfr[n4][1], acc[m4][n4], 0, 0, 0);
            }
        __builtin_amdgcn_s_setprio(0);
        // drain prev-tile Sy (a1,a3) — the 2 oldest of 8 outstanding — before R2 reads them
        if (pf) { WAIT_VM6(); } else { WAIT_VM0(); }
        PH_BAR();

        // ===== Region 2: reads A-h1(8); stage Sy={a1,a3}; MFMA acc[4..7][*] =====
#pragma unroll
        for (int m4 = 0; m4 < 4; ++m4) {
            af[m4][0] = LDA8(cur, m_off + (4 + m4) * 16 + fr, 0);
            af[m4][1] = LDA8(cur, m_off + (4 + m4) * 16 + fr, 1);
        }
        if (pf) { stA(1); stA(3); }
        __builtin_amdgcn_s_setprio(1);
#pragma unroll
        for (int m4 = 0; m4 < 4; ++m4)
#pragma unroll
            for (int n4 = 0; n4 < 4; ++n4) {
                acc[4 + m4][n4] = __builtin_amdgcn_mfma_f32_16x16x32_bf16(af[m4][0], bfr[n4][0], acc[4 + m4][n4], 0, 0, 0);
                acc[4 + m4][n4] = __builtin_amdgcn_mfma_f32_16x16x32_bf16(af[m4][1], bfr[n4][1], acc[4 + m4][n4], 0, 0, 0);
            }
        __builtin_amdgcn_s_setprio(0);
        // drain Sx of this tile (6 oldest), leave Sy (a1,a3) in flight across the boundary
        if (pf) { WAIT_VM2(); }
        PH_BAR();
    }
#undef LDA8
#undef LDB8

    // ---- epilogue ----
#pragma unroll
    for (int ni = 0; ni < 4; ++ni) {
        const int nn = n0 + n_off + ni * 16 + fr;
        const float scv = scale[nn];
        const float bsv = bias[nn];
#pragma unroll
        for (int mi = 0; mi < 8; ++mi) {
            const int mb = p0 + m_off + mi * 16 + qd * 4;
#pragma unroll
            for (int r = 0; r < 4; ++r) {
                const int p = mb + r;
                const float y = acc[mi][ni][r] * scv + bsv;
                const float a = y / (1.f + __expf(-y));
                if (MODE == M_SA1) {
                    const int bb = p / 1600; const int s = p - bb * 1600;
                    const int oy = s / 40, ox = s - (s / 40) * 40;
                    outb[(((size_t)(bb * 42 + oy + 1)) * 42 + ox + 1) * 256 + nn] = f2b(a);
                } else if (MODE == M_SA2) {
                    const int bb = p / 1600; const int s = p - bb * 1600;
                    const int oy = s / 40, ox = s - (s / 40) * 40;
                    const size_t roff = (((size_t)(bb * 42 + oy + 1)) * 42 + ox + 1) * 256 + nn;
                    outb[(size_t)p * 256 + nn] = f2b(a + b2f(resid[roff]));
                } else if (MODE == M_C3) {
                    const int bb = p / 1600; const int s = p - bb * 1600;
                    const int oy = s / 40, ox = s - (s / 40) * 40;
                    const size_t roff = (((size_t)(bb * 42 + oy + 1)) * 42 + ox + 1) * 512 + nn;
                    outb[(size_t)p * 512 + nn] = f2b(a + b2f(resid[roff]));
                } else { // M_CONV2
                    outb[(size_t)p * 512 + nn] = f2b(a);
                }
            }
        }
    }
}

// single-mode wrapper (SA2: 200 blocks, CONV2: 400 blocks)
template <int MODE>
__global__ __launch_bounds__(512, 2)
void conv_mfma256(const bf16* __restrict__ in, const bf16* __restrict__ in2,
                  const bf16* __restrict__ wr,
                  const float* __restrict__ scale, const float* __restrict__ bias,
                  const bf16* __restrict__ resid,
                  bf16* __restrict__ outb)
{
    __shared__ bf16 Al[2][256][64];
    __shared__ bf16 Bl[2][256][64];
    int mtile, ntile;
    if (MODE == M_CONV2 || MODE == M_C3) { mtile = blockIdx.x >> 1; ntile = blockIdx.x & 1; }
    else { mtile = blockIdx.x; ntile = 0; }
    conv_body256<MODE>(in, in2, wr, scale, bias, resid, outb,
                       &Al[0][0][0], &Bl[0][0][0], mtile, ntile);
}

// merged C3 + SA1 launch: C3 (long blocks) first for LPT dispatch, SA1 backfills
__global__ __launch_bounds__(512, 2)
void conv_c3_sa1(const bf16* __restrict__ attn, const bf16* __restrict__ wc3,
                 const float* __restrict__ c3_s, const float* __restrict__ c3_b,
                 bf16* __restrict__ x2o,
                 const bf16* __restrict__ xca, const bf16* __restrict__ wsa1,
                 const float* __restrict__ sa1_s, const float* __restrict__ sa1_b,
                 bf16* __restrict__ tbuf)
{
    __shared__ bf16 Al[2][256][64];
    __shared__ bf16 Bl[2][256][64];
    const int bx = blockIdx.x;
    if (bx < 400) {
        conv_body256<M_C3>(attn, nullptr, wc3, c3_s, c3_b, attn, x2o,
                           &Al[0][0][0], &Bl[0][0][0], bx >> 1, bx & 1);
    } else {
        conv_body256<M_SA1>(xca, nullptr, wsa1, sa1_s, sa1_b, nullptr, tbuf,
                            &Al[0][0][0], &Bl[0][0][0], bx - 400, 0);
    }
}

extern "C" void kernel_launch(void* const* d_in, const int* in_sizes, int n_in,
                              void* d_out, int out_size, void* d_ws, size_t ws_size,
                              hipStream_t stream)
{
    const float* x1      = (const float*)d_in[0];
    const float* x2      = (const float*)d_in[1];
    const float* q_w     = (const float*)d_in[2];
    const float* q_s     = (const float*)d_in[3];
    const float* q_b     = (const float*)d_in[4];
    const float* key_w   = (const float*)d_in[5];
    const float* ca_w1   = (const float*)d_in[6];
    const float* ca_b1   = (const float*)d_in[7];
    const float* ca_w2   = (const float*)d_in[8];
    const float* ca_b2   = (const float*)d_in[9];
    const float* sa1_w   = (const float*)d_in[10];
    const float* sa1_s   = (const float*)d_in[11];
    const float* sa1_b   = (const float*)d_in[12];
    const float* sa2_w   = (const float*)d_in[13];
    const float* sa2_s   = (const float*)d_in[14];
    const float* sa2_b   = (const float*)d_in[15];
    const float* conv2_w = (const float*)d_in[16];
    const float* conv2_s = (const float*)d_in[17];
    const float* conv2_b = (const float*)d_in[18];
    const float* c3_w    = (const float*)d_in[19];
    const float* c3_s    = (const float*)d_in[20];
    const float* c3_b    = (const float*)d_in[21];

    char* ws = (char*)d_ws;
    // workspace layout (bytes) — padded NHWC buffers, aggressive aliasing; peak 213,254,144
    const size_t o_x1n  = 0;                 // 32*22*22*512 bf16 : 15,859,712 (halo)
    const size_t o_x2n  = 15859712;          // 32*1600*512 bf16  : 52,428,800 (x2o alias after attn)
    const size_t o_attn = 68288512;          // 32*42*42*512 bf16 : 57,802,752 (halo; x1o alias after C3)
    const size_t o_xca  = 126091264;         // 32*42*42*256 bf16 : 28,901,376 (halo; live through SA2)
    const size_t o_tbuf = 154992640;         // 32*42*42*256 bf16 : 28,901,376 (halo; k/q/wkey alias before SA1)
    const size_t o_a2   = 183894016;         // 32*1600*256 bf16  : 26,214,400 (kp/wq/wc3 alias before SA2)
    const size_t o_ws1  = 210108416;         // 256*2304 bf16 : 1,179,648
    const size_t o_ws2  = 211288064;         // 256*2304 bf16 : 1,179,648
    const size_t o_wc2  = 212467712;         // 512*768  bf16 :   786,432
    // aliases
    const size_t o_k    = o_tbuf;            // 3,276,800 f32
    const size_t o_q    = o_tbuf + 3276800;  // 3,276,800 f32
    const size_t o_wkey = o_tbuf + 6553600;  //   262,144 bf16
    const size_t o_kp   = o_a2;              // 3,276,800 bf16
    const size_t o_wq   = o_a2 + 3276800;    // 2,359,296 bf16
    const size_t o_wc3  = o_a2 + 5636096;    // 4,718,592 bf16 (dead before SA2 writes a2)

    bf16*  x1n    = (bf16*)(ws + o_x1n);
    bf16*  x2n    = (bf16*)(ws + o_x2n);
    float* k_attn = (float*)(ws + o_k);
    float* q_attn = (float*)(ws + o_q);
    bf16*  attn   = (bf16*)(ws + o_attn);
    bf16*  xca    = (bf16*)(ws + o_xca);
    bf16*  tbuf   = (bf16*)(ws + o_tbuf);
    bf16*  a2     = (bf16*)(ws + o_a2);
    bf16*  wq     = (bf16*)(ws + o_wq);
    bf16*  wc3    = (bf16*)(ws + o_wc3);
    bf16*  wsa1   = (bf16*)(ws + o_ws1);
    bf16*  wsa2   = (bf16*)(ws + o_ws2);
    bf16*  kp     = (bf16*)(ws + o_kp);
    bf16*  wkey   = (bf16*)(ws + o_wkey);
    bf16*  wc2    = (bf16*)(ws + o_wc2);
    bf16*  x2o    = (bf16*)(ws + o_x2n);     // alias: x2n dead after attn_kernel
    bf16*  x1o    = (bf16*)(ws + o_attn);    // alias: attn dead after C3

    const dim3 blk(256);
    const dim3 blk512(512);

    halo_zero<<<dim3(32, 22), blk, 0, stream>>>(x1n, 20, 512);
    halo_zero<<<dim3(32, 42), blk, 0, stream>>>(xca, 40, 256);
    halo_zero<<<dim3(32, 42), blk, 0, stream>>>(attn, 40, 512);

    nchw_to_nhwc<<<dim3(32, 7, 8), blk, 0, stream>>>(x1, x1n, 512, 20, 20, 1);
    nchw_to_nhwc<<<dim3(32, 25, 8), blk, 0, stream>>>(x2, x2n, 512, 40, 40, 0);
    reorder_w<<<4608, blk, 0, stream>>>(q_w,  wq,   512, 256 * 512 * 9);
    reorder_w<<<9216, blk, 0, stream>>>(c3_w, wc3,  512, 512 * 512 * 9);
    reorder_w<<<2304, blk, 0, stream>>>(sa1_w, wsa1, 256, 256 * 256 * 9);
    reorder_w<<<2304, blk, 0, stream>>>(sa2_w, wsa2, 256, 256 * 256 * 9);
    f32_to_bf16<<<512, blk, 0, stream>>>(key_w, wkey, 256 * 512);
    f32_to_bf16<<<1536, blk, 0, stream>>>(conv2_w, wc2, 512 * 768);
    pool_kp<<<3200, blk, 0, stream>>>(x2n, kp);

    conv_mfma<M_KPROJ><<<dim3(25, 2), blk, 0, stream>>>(kp, wkey, nullptr, nullptr, k_attn);
    conv_mfma<M_QCONV><<<dim3(25, 2), blk, 0, stream>>>(x1n, wq, q_s, q_b, q_attn);

    attn_kernel<<<256, blk, 0, stream>>>(q_attn, k_attn, x2n, attn);

    // k/q/wkey dead now; zero tbuf halo before SA1 writes into it
    halo_zero<<<dim3(32, 42), blk, 0, stream>>>(tbuf, 40, 256);

    ca_mlp<<<12800, blk, 0, stream>>>(x1n, ca_w1, ca_b1, ca_w2, ca_b2, xca);

    // merged: C3 (blocks 0-399) + SA1 (blocks 400-599) — independent, LPT-balanced
    conv_c3_sa1<<<600, blk512, 0, stream>>>(attn, wc3, c3_s, c3_b, x2o,
                                            xca, wsa1, sa1_s, sa1_b, tbuf);

    conv_mfma256<M_SA2><<<200, blk512, 0, stream>>>(tbuf, nullptr, wsa2,
        sa2_s, sa2_b, xca, a2);
    conv_mfma256<M_CONV2><<<400, blk512, 0, stream>>>(x1n, a2, wc2,
        conv2_s, conv2_b, nullptr, x1o);

    pack_out<<<dim3(32, 25, 16), blk, 0, stream>>>(x1o, x2o, (float*)d_out);

    (void)in_sizes; (void)n_in; (void)out_size; (void)ws_size;
}